// Round 1
// baseline (10201.022 us; speedup 1.0000x reference)
//
#include <hip/hip_runtime.h>
#include <hip/hip_bf16.h>
#include <math.h>

// Problem constants (match reference)
#define LAYERS 4
#define DMODEL 768
#define NHEAD 12
#define HDIM 64
#define FFDIM 3072
#define VOCAB 32000
#define NCLS 2
#define BATCH 8
#define SEQ 512
#define NTOK (BATCH * SEQ)   // 4096

// ---------------------------------------------------------------------------
// Embedding + positional encoding: x[n,d] = emb[text[n]][d]*sqrt(D) + PE(s,d)
// ---------------------------------------------------------------------------
__global__ __launch_bounds__(256) void embed_kernel(
    const int* __restrict__ text, const float* __restrict__ emb,
    float* __restrict__ x) {
  int n = blockIdx.x;          // token index
  int t = threadIdx.x;
  int tok = text[n];
  int s = n % SEQ;
  const float sqrtD = 27.712812921102035f;          // sqrt(768)
  const float nlog10k_over_d = -9.210340371976184f / 768.0f;  // -ln(10000)/768
  #pragma unroll
  for (int i = 0; i < 3; ++i) {
    int d = t + i * 256;
    int j = d >> 1;
    float freq = expf((float)(2 * j) * nlog10k_over_d);
    float ang = (float)s * freq;
    float pe = (d & 1) ? cosf(ang) : sinf(ang);
    x[(size_t)n * DMODEL + d] = emb[(size_t)tok * DMODEL + d] * sqrtD + pe;
  }
}

// ---------------------------------------------------------------------------
// Generic f32 GEMM: C[M,N] = A[M,K] @ W[K,N] + bias[N]  (optional ReLU)
// 64x64 tile, 256 threads, 4x4 microtile, K-step 16. M%64==0,N%64==0,K%16==0.
// ---------------------------------------------------------------------------
__global__ __launch_bounds__(256) void gemm_bias_kernel(
    const float* __restrict__ A, const float* __restrict__ W,
    const float* __restrict__ bias, float* __restrict__ Cmat,
    int M, int K, int Nn, int relu) {
  __shared__ float As[16][64];   // [k][m]
  __shared__ float Ws[16][64];   // [k][n]
  int tx = threadIdx.x, ty = threadIdx.y;
  int tid = ty * 16 + tx;
  int m0 = blockIdx.y * 64, n0 = blockIdx.x * 64;
  float acc[4][4] = {};

  for (int k0 = 0; k0 < K; k0 += 16) {
    {  // A tile 64x16, one float4 per thread along K, store transposed
      int row = tid >> 2;
      int kq = (tid & 3) * 4;
      float4 av = *(const float4*)(A + (size_t)(m0 + row) * K + k0 + kq);
      As[kq + 0][row] = av.x; As[kq + 1][row] = av.y;
      As[kq + 2][row] = av.z; As[kq + 3][row] = av.w;
    }
    {  // W tile 16x64, one float4 per thread along N
      int kk = tid >> 4;
      int nq = (tid & 15) * 4;
      float4 wv = *(const float4*)(W + (size_t)(k0 + kk) * Nn + n0 + nq);
      *(float4*)&Ws[kk][nq] = wv;
    }
    __syncthreads();
    #pragma unroll
    for (int kk = 0; kk < 16; ++kk) {
      float a4[4], w4[4];
      *(float4*)a4 = *(const float4*)&As[kk][ty * 4];
      *(float4*)w4 = *(const float4*)&Ws[kk][tx * 4];
      #pragma unroll
      for (int i = 0; i < 4; ++i)
        #pragma unroll
        for (int j = 0; j < 4; ++j)
          acc[i][j] += a4[i] * w4[j];
    }
    __syncthreads();
  }

  int n = n0 + tx * 4;
  float4 bv = *(const float4*)(bias + n);
  #pragma unroll
  for (int i = 0; i < 4; ++i) {
    int m = m0 + ty * 4 + i;
    float4 r;
    r.x = acc[i][0] + bv.x; r.y = acc[i][1] + bv.y;
    r.z = acc[i][2] + bv.z; r.w = acc[i][3] + bv.w;
    if (relu) {
      r.x = fmaxf(r.x, 0.f); r.y = fmaxf(r.y, 0.f);
      r.z = fmaxf(r.z, 0.f); r.w = fmaxf(r.w, 0.f);
    }
    *(float4*)(Cmat + (size_t)m * Nn + n) = r;
  }
}

// ---------------------------------------------------------------------------
// Fused attention: one block per (b,h,q_row), 128 threads.
// q,k,v layouts: [N, D] with head h at cols h*64..h*64+63.
// ---------------------------------------------------------------------------
__global__ __launch_bounds__(128) void attention_kernel(
    const float* __restrict__ q, const float* __restrict__ k,
    const float* __restrict__ v, const int* __restrict__ mask,
    float* __restrict__ out) {
  int idx = blockIdx.x;
  int sq = idx % SEQ;
  int h = (idx / SEQ) % NHEAD;
  int b = idx / (SEQ * NHEAD);
  int t = threadIdx.x;  // 0..127

  __shared__ float qs[64];
  __shared__ float att[SEQ];
  __shared__ float red[128];

  const float* qrow = q + (size_t)(b * SEQ + sq) * DMODEL + h * HDIM;
  if (t < 64) qs[t] = qrow[t];
  __syncthreads();

  // scores: 4 keys per thread
  float sc[4];
  #pragma unroll
  for (int i = 0; i < 4; ++i) {
    int key = t + i * 128;
    const float* krow = k + (size_t)(b * SEQ + key) * DMODEL + h * HDIM;
    float s_ = 0.f;
    for (int d = 0; d < HDIM; ++d) s_ += qs[d] * krow[d];
    s_ *= 0.125f;  // 1/sqrt(64)
    if (mask[b * SEQ + key] == 0) s_ = -1e9f;
    sc[i] = s_;
  }
  // block max
  float m = fmaxf(fmaxf(sc[0], sc[1]), fmaxf(sc[2], sc[3]));
  red[t] = m; __syncthreads();
  for (int off = 64; off; off >>= 1) {
    if (t < off) red[t] = fmaxf(red[t], red[t + off]);
    __syncthreads();
  }
  m = red[0];
  __syncthreads();
  // exp + sum
  float psum = 0.f;
  #pragma unroll
  for (int i = 0; i < 4; ++i) {
    float e = expf(sc[i] - m);
    att[t + i * 128] = e;
    psum += e;
  }
  red[t] = psum; __syncthreads();
  for (int off = 64; off; off >>= 1) {
    if (t < off) red[t] += red[t + off];
    __syncthreads();
  }
  float inv = 1.0f / red[0];
  __syncthreads();

  // output: 128 threads = 64 dims x 2 key-halves
  int d = t & 63, half = t >> 6;
  float acc = 0.f;
  for (int key = half * 256; key < half * 256 + 256; ++key) {
    acc += att[key] * v[(size_t)(b * SEQ + key) * DMODEL + h * HDIM + d];
  }
  red[t] = acc; __syncthreads();
  if (t < 64)
    out[(size_t)(b * SEQ + sq) * DMODEL + h * HDIM + t] = (red[t] + red[t + 64]) * inv;
}

// ---------------------------------------------------------------------------
// LayerNorm (optionally with residual): out[n,:] = LN(x[n,:] (+ o[n,:]))*g + b
// One block per token, 256 threads, 3 elems each (D=768).
// ---------------------------------------------------------------------------
__global__ __launch_bounds__(256) void ln_kernel(
    const float* __restrict__ x, const float* __restrict__ o,
    float* __restrict__ out, const float* __restrict__ g,
    const float* __restrict__ bta) {
  int n = blockIdx.x;
  int t = threadIdx.x;
  __shared__ float red[256];
  float vals[3];
  float sum = 0.f;
  #pragma unroll
  for (int i = 0; i < 3; ++i) {
    int d = t + i * 256;
    float val = x[(size_t)n * DMODEL + d];
    if (o) val += o[(size_t)n * DMODEL + d];
    vals[i] = val;
    sum += val;
  }
  red[t] = sum; __syncthreads();
  for (int off = 128; off; off >>= 1) {
    if (t < off) red[t] += red[t + off];
    __syncthreads();
  }
  float mu = red[0] * (1.0f / DMODEL);
  __syncthreads();
  float vs = 0.f;
  #pragma unroll
  for (int i = 0; i < 3; ++i) {
    float dlt = vals[i] - mu;
    vs += dlt * dlt;
  }
  red[t] = vs; __syncthreads();
  for (int off = 128; off; off >>= 1) {
    if (t < off) red[t] += red[t + off];
    __syncthreads();
  }
  float rstd = rsqrtf(red[0] * (1.0f / DMODEL) + 1e-5f);
  __syncthreads();
  #pragma unroll
  for (int i = 0; i < 3; ++i) {
    int d = t + i * 256;
    out[(size_t)n * DMODEL + d] = (vals[i] - mu) * rstd * g[d] + bta[d];
  }
}

// ---------------------------------------------------------------------------
// Mean-pool over sequence: pooled[b,d] = mean_s xin[b,s,d]
// grid = B * (D/256) blocks
// ---------------------------------------------------------------------------
__global__ __launch_bounds__(256) void pool_kernel(
    const float* __restrict__ xin, float* __restrict__ pooled) {
  int blk = blockIdx.x;
  int b = blk / (DMODEL / 256);
  int dc = blk % (DMODEL / 256);
  int d = dc * 256 + threadIdx.x;
  float s_ = 0.f;
  for (int s = 0; s < SEQ; ++s)
    s_ += xin[(size_t)(b * SEQ + s) * DMODEL + d];
  pooled[b * DMODEL + d] = s_ * (1.0f / SEQ);
}

// ---------------------------------------------------------------------------
// Classifier: logits = pooled @ Wfc + bfc; out = log_softmax(logits)
// One block per batch row.
// ---------------------------------------------------------------------------
__global__ __launch_bounds__(256) void classifier_kernel(
    const float* __restrict__ pooled, const float* __restrict__ Wfc,
    const float* __restrict__ bfc, float* __restrict__ out) {
  int b = blockIdx.x;
  int t = threadIdx.x;
  __shared__ float s0[256], s1[256];
  float acc0 = 0.f, acc1 = 0.f;
  for (int d = t; d < DMODEL; d += 256) {
    float p = pooled[b * DMODEL + d];
    acc0 += p * Wfc[d * NCLS + 0];
    acc1 += p * Wfc[d * NCLS + 1];
  }
  s0[t] = acc0; s1[t] = acc1; __syncthreads();
  for (int off = 128; off; off >>= 1) {
    if (t < off) { s0[t] += s0[t + off]; s1[t] += s1[t + off]; }
    __syncthreads();
  }
  if (t == 0) {
    float l0 = s0[0] + bfc[0], l1 = s1[0] + bfc[1];
    float m = fmaxf(l0, l1);
    float lse = m + logf(expf(l0 - m) + expf(l1 - m));
    out[b * NCLS + 0] = l0 - lse;
    out[b * NCLS + 1] = l1 - lse;
  }
}

// ---------------------------------------------------------------------------
extern "C" void kernel_launch(void* const* d_in, const int* in_sizes, int n_in,
                              void* d_out, int out_size, void* d_ws, size_t ws_size,
                              hipStream_t stream) {
  const int*   text  = (const int*)d_in[0];
  const int*   mask  = (const int*)d_in[1];
  const float* emb   = (const float*)d_in[2];
  const float* Wq    = (const float*)d_in[3];
  const float* bq    = (const float*)d_in[4];
  const float* Wk    = (const float*)d_in[5];
  const float* bk    = (const float*)d_in[6];
  const float* Wv    = (const float*)d_in[7];
  const float* bv    = (const float*)d_in[8];
  const float* Wo    = (const float*)d_in[9];
  const float* bo    = (const float*)d_in[10];
  const float* W1    = (const float*)d_in[11];
  const float* b1    = (const float*)d_in[12];
  const float* W2    = (const float*)d_in[13];
  const float* b2    = (const float*)d_in[14];
  const float* ln1_g = (const float*)d_in[15];
  const float* ln1_b = (const float*)d_in[16];
  const float* ln2_g = (const float*)d_in[17];
  const float* ln2_b = (const float*)d_in[18];
  const float* lnf_g = (const float*)d_in[19];
  const float* lnf_b = (const float*)d_in[20];
  const float* Wfc   = (const float*)d_in[21];
  const float* bfc   = (const float*)d_in[22];

  const size_t ND = (size_t)NTOK * DMODEL;   // 3,145,728
  const size_t NF = (size_t)NTOK * FFDIM;    // 12,582,912
  float* ws = (float*)d_ws;
  float* x      = ws;            // [N,D]
  float* q      = x + ND;        // [N,D]  (also o-proj / ffn2 output)
  float* kbuf   = q + ND;        // [N,D]
  float* vbuf   = kbuf + ND;     // [N,D]
  float* h1     = vbuf + ND;     // [N,FF]; attention output aliased here
  float* ao     = h1;            //   (dead when FFN1 runs)
  float* pooled = h1 + NF;       // [B,D]

  dim3 blk2(16, 16);
  dim3 gD(DMODEL / 64, NTOK / 64);   // N-out = 768
  dim3 gF(FFDIM / 64, NTOK / 64);    // N-out = 3072

  embed_kernel<<<NTOK, 256, 0, stream>>>(text, emb, x);

  for (int l = 0; l < LAYERS; ++l) {
    const float* wq = Wq + (size_t)l * DMODEL * DMODEL;
    const float* wk = Wk + (size_t)l * DMODEL * DMODEL;
    const float* wv = Wv + (size_t)l * DMODEL * DMODEL;
    const float* wo = Wo + (size_t)l * DMODEL * DMODEL;
    const float* w1 = W1 + (size_t)l * DMODEL * FFDIM;
    const float* w2 = W2 + (size_t)l * FFDIM * DMODEL;

    gemm_bias_kernel<<<gD, blk2, 0, stream>>>(x, wq, bq + l * DMODEL, q,    NTOK, DMODEL, DMODEL, 0);
    gemm_bias_kernel<<<gD, blk2, 0, stream>>>(x, wk, bk + l * DMODEL, kbuf, NTOK, DMODEL, DMODEL, 0);
    gemm_bias_kernel<<<gD, blk2, 0, stream>>>(x, wv, bv + l * DMODEL, vbuf, NTOK, DMODEL, DMODEL, 0);

    attention_kernel<<<BATCH * NHEAD * SEQ, 128, 0, stream>>>(q, kbuf, vbuf, mask, ao);

    // o-projection into q (q dead now)
    gemm_bias_kernel<<<gD, blk2, 0, stream>>>(ao, wo, bo + l * DMODEL, q, NTOK, DMODEL, DMODEL, 0);
    // x = LN(x + o)
    ln_kernel<<<NTOK, 256, 0, stream>>>(x, q, x, ln1_g + l * DMODEL, ln1_b + l * DMODEL);
    // ffn
    gemm_bias_kernel<<<gF, blk2, 0, stream>>>(x, w1, b1 + l * FFDIM, h1, NTOK, DMODEL, FFDIM, 1);
    gemm_bias_kernel<<<gD, blk2, 0, stream>>>(h1, w2, b2 + l * DMODEL, q, NTOK, FFDIM, DMODEL, 0);
    // x = LN(x + ffn)
    ln_kernel<<<NTOK, 256, 0, stream>>>(x, q, x, ln2_g + l * DMODEL, ln2_b + l * DMODEL);
  }

  // final LN into q, pool, classify
  ln_kernel<<<NTOK, 256, 0, stream>>>(x, nullptr, q, lnf_g, lnf_b);
  pool_kernel<<<BATCH * (DMODEL / 256), 256, 0, stream>>>(q, pooled);
  classifier_kernel<<<BATCH, 256, 0, stream>>>(pooled, Wfc, bfc, (float*)d_out);
}

// Round 2
// 3982.097 us; speedup vs baseline: 2.5617x; 2.5617x over previous
//
#include <hip/hip_runtime.h>
#include <hip/hip_bf16.h>
#include <math.h>

// Problem constants (match reference)
#define LAYERS 4
#define DMODEL 768
#define NHEAD 12
#define HDIM 64
#define FFDIM 3072
#define VOCAB 32000
#define NCLS 2
#define BATCH 8
#define SEQ 512
#define NTOK (BATCH * SEQ)   // 4096

// ---------------------------------------------------------------------------
// Embedding + positional encoding: x[n,d] = emb[text[n]][d]*sqrt(D) + PE(s,d)
// ---------------------------------------------------------------------------
__global__ __launch_bounds__(256) void embed_kernel(
    const int* __restrict__ text, const float* __restrict__ emb,
    float* __restrict__ x) {
  int n = blockIdx.x;          // token index
  int t = threadIdx.x;
  int tok = text[n];
  int s = n % SEQ;
  const float sqrtD = 27.712812921102035f;          // sqrt(768)
  const float nlog10k_over_d = -9.210340371976184f / 768.0f;  // -ln(10000)/768
  #pragma unroll
  for (int i = 0; i < 3; ++i) {
    int d = t + i * 256;
    int j = d >> 1;
    float freq = expf((float)(2 * j) * nlog10k_over_d);
    float ang = (float)s * freq;
    float pe = (d & 1) ? cosf(ang) : sinf(ang);
    x[(size_t)n * DMODEL + d] = emb[(size_t)tok * DMODEL + d] * sqrtD + pe;
  }
}

// ---------------------------------------------------------------------------
// Generic f32 GEMM: C[M,N] = A[M,K] @ W[K,N] + bias[N]  (optional ReLU)
// 64x64 tile, 256 threads, 4x4 microtile, K-step 16. M%64==0,N%64==0,K%16==0.
// ---------------------------------------------------------------------------
__global__ __launch_bounds__(256) void gemm_bias_kernel(
    const float* __restrict__ A, const float* __restrict__ W,
    const float* __restrict__ bias, float* __restrict__ Cmat,
    int M, int K, int Nn, int relu) {
  __shared__ float As[16][64];   // [k][m]
  __shared__ float Ws[16][64];   // [k][n]
  int tx = threadIdx.x, ty = threadIdx.y;
  int tid = ty * 16 + tx;
  int m0 = blockIdx.y * 64, n0 = blockIdx.x * 64;
  float acc[4][4] = {};

  for (int k0 = 0; k0 < K; k0 += 16) {
    {  // A tile 64x16, one float4 per thread along K, store transposed
      int row = tid >> 2;
      int kq = (tid & 3) * 4;
      float4 av = *(const float4*)(A + (size_t)(m0 + row) * K + k0 + kq);
      As[kq + 0][row] = av.x; As[kq + 1][row] = av.y;
      As[kq + 2][row] = av.z; As[kq + 3][row] = av.w;
    }
    {  // W tile 16x64, one float4 per thread along N
      int kk = tid >> 4;
      int nq = (tid & 15) * 4;
      float4 wv = *(const float4*)(W + (size_t)(k0 + kk) * Nn + n0 + nq);
      *(float4*)&Ws[kk][nq] = wv;
    }
    __syncthreads();
    #pragma unroll
    for (int kk = 0; kk < 16; ++kk) {
      float a4[4], w4[4];
      *(float4*)a4 = *(const float4*)&As[kk][ty * 4];
      *(float4*)w4 = *(const float4*)&Ws[kk][tx * 4];
      #pragma unroll
      for (int i = 0; i < 4; ++i)
        #pragma unroll
        for (int j = 0; j < 4; ++j)
          acc[i][j] += a4[i] * w4[j];
    }
    __syncthreads();
  }

  int n = n0 + tx * 4;
  float4 bv = *(const float4*)(bias + n);
  #pragma unroll
  for (int i = 0; i < 4; ++i) {
    int m = m0 + ty * 4 + i;
    float4 r;
    r.x = acc[i][0] + bv.x; r.y = acc[i][1] + bv.y;
    r.z = acc[i][2] + bv.z; r.w = acc[i][3] + bv.w;
    if (relu) {
      r.x = fmaxf(r.x, 0.f); r.y = fmaxf(r.y, 0.f);
      r.z = fmaxf(r.z, 0.f); r.w = fmaxf(r.w, 0.f);
    }
    *(float4*)(Cmat + (size_t)m * Nn + n) = r;
  }
}

// ---------------------------------------------------------------------------
// Tiled flash-style attention: one block per (b, h, 64-query tile).
// 256 threads (16x16), 4x4 microtile for both QK^T and PV.
// Online softmax: per-query running max m and denom l in LDS.
// q,k,v layouts: [N, D] with head h at cols h*64..h*64+63.
// ---------------------------------------------------------------------------
#define QT 64
#define KT 64
__global__ __launch_bounds__(256) void attention_tiled_kernel(
    const float* __restrict__ q, const float* __restrict__ k,
    const float* __restrict__ v, const int* __restrict__ mask,
    float* __restrict__ out) {
  int blk = blockIdx.x;
  int qt0 = (blk % (SEQ / QT)) * QT;
  int h = (blk / (SEQ / QT)) % NHEAD;
  int b = blk / ((SEQ / QT) * NHEAD);

  __shared__ float qs[HDIM][68];   // [dim][query]  (transposed)
  __shared__ float ks[HDIM][68];   // [dim][key]    (transposed)
  __shared__ float vs[KT][68];     // [key][dim]
  __shared__ float ps[KT][65];     // [key][query]  (pitch 65: col scan conflict-free)
  __shared__ float m_s[QT], l_s[QT], corr_s[QT];

  int tid = threadIdx.x;
  int tx = tid & 15, ty = tid >> 4;

  const size_t headoff = (size_t)h * HDIM;

  // ---- load Q tile transposed ----
  {
    int c0 = (tid & 15) * 4;
    #pragma unroll
    for (int it = 0; it < 4; ++it) {
      int r = (tid >> 4) + it * 16;
      float4 qv = *(const float4*)(q + (size_t)(b * SEQ + qt0 + r) * DMODEL + headoff + c0);
      qs[c0 + 0][r] = qv.x; qs[c0 + 1][r] = qv.y;
      qs[c0 + 2][r] = qv.z; qs[c0 + 3][r] = qv.w;
    }
  }
  if (tid < QT) { m_s[tid] = -3.0e38f; l_s[tid] = 0.0f; }

  float o[4][4] = {};

  for (int kt = 0; kt < SEQ / KT; ++kt) {
    __syncthreads();
    // ---- load K tile (transposed) and V tile (natural) ----
    {
      int c0 = (tid & 15) * 4;
      #pragma unroll
      for (int it = 0; it < 4; ++it) {
        int r = (tid >> 4) + it * 16;
        const float* krow = k + (size_t)(b * SEQ + kt * KT + r) * DMODEL + headoff;
        float4 kv = *(const float4*)(krow + c0);
        ks[c0 + 0][r] = kv.x; ks[c0 + 1][r] = kv.y;
        ks[c0 + 2][r] = kv.z; ks[c0 + 3][r] = kv.w;
        const float* vrow = v + (size_t)(b * SEQ + kt * KT + r) * DMODEL + headoff;
        *(float4*)&vs[r][c0] = *(const float4*)(vrow + c0);
      }
    }
    __syncthreads();

    // ---- scores S = Q K^T / 8  (+mask), store transposed ps[key][query] ----
    {
      float s[4][4] = {};
      #pragma unroll 16
      for (int kk = 0; kk < HDIM; ++kk) {
        float a4[4], w4[4];
        *(float4*)a4 = *(const float4*)&qs[kk][ty * 4];
        *(float4*)w4 = *(const float4*)&ks[kk][tx * 4];
        #pragma unroll
        for (int i = 0; i < 4; ++i)
          #pragma unroll
          for (int j = 0; j < 4; ++j)
            s[i][j] += a4[i] * w4[j];
      }
      #pragma unroll
      for (int j = 0; j < 4; ++j) {
        int key = kt * KT + tx * 4 + j;
        int msk = mask[b * SEQ + key];
        #pragma unroll
        for (int i = 0; i < 4; ++i) {
          float val = s[i][j] * 0.125f;
          if (msk == 0) val = -1e9f;
          ps[tx * 4 + j][ty * 4 + i] = val;
        }
      }
    }
    __syncthreads();

    // ---- online softmax update: 4 threads per query ----
    {
      int qq = tid >> 2;        // 0..63
      int part = tid & 3;       // 0..3
      float mp = -3.0e38f;
      #pragma unroll
      for (int kk = part * 16; kk < part * 16 + 16; ++kk)
        mp = fmaxf(mp, ps[kk][qq]);
      mp = fmaxf(mp, __shfl_xor(mp, 1));
      mp = fmaxf(mp, __shfl_xor(mp, 2));
      float m_old = m_s[qq];
      float m_new = fmaxf(m_old, mp);
      float sp = 0.f;
      #pragma unroll
      for (int kk = part * 16; kk < part * 16 + 16; ++kk) {
        float e = expf(ps[kk][qq] - m_new);
        ps[kk][qq] = e;
        sp += e;
      }
      sp += __shfl_xor(sp, 1);
      sp += __shfl_xor(sp, 2);
      if (part == 0) {
        float corr = expf(m_old - m_new);
        m_s[qq] = m_new;
        l_s[qq] = l_s[qq] * corr + sp;
        corr_s[qq] = corr;
      }
    }
    __syncthreads();

    // ---- O = O*corr + P V ----
    {
      #pragma unroll
      for (int i = 0; i < 4; ++i) {
        float c = corr_s[ty * 4 + i];
        #pragma unroll
        for (int j = 0; j < 4; ++j) o[i][j] *= c;
      }
      #pragma unroll 8
      for (int kk = 0; kk < KT; ++kk) {
        float w4[4];
        *(float4*)w4 = *(const float4*)&vs[kk][tx * 4];
        float a0 = ps[kk][ty * 4 + 0];
        float a1 = ps[kk][ty * 4 + 1];
        float a2 = ps[kk][ty * 4 + 2];
        float a3 = ps[kk][ty * 4 + 3];
        #pragma unroll
        for (int j = 0; j < 4; ++j) {
          o[0][j] += a0 * w4[j];
          o[1][j] += a1 * w4[j];
          o[2][j] += a2 * w4[j];
          o[3][j] += a3 * w4[j];
        }
      }
    }
  }
  __syncthreads();

  // ---- write out: o / l ----
  #pragma unroll
  for (int i = 0; i < 4; ++i) {
    int qq = ty * 4 + i;
    float inv = 1.0f / l_s[qq];
    float4 r;
    r.x = o[i][0] * inv; r.y = o[i][1] * inv;
    r.z = o[i][2] * inv; r.w = o[i][3] * inv;
    *(float4*)(out + (size_t)(b * SEQ + qt0 + qq) * DMODEL + headoff + tx * 4) = r;
  }
}

// ---------------------------------------------------------------------------
// LayerNorm (optionally with residual): out[n,:] = LN(x[n,:] (+ o[n,:]))*g + b
// One block per token, 256 threads, 3 elems each (D=768).
// ---------------------------------------------------------------------------
__global__ __launch_bounds__(256) void ln_kernel(
    const float* __restrict__ x, const float* __restrict__ o,
    float* __restrict__ out, const float* __restrict__ g,
    const float* __restrict__ bta) {
  int n = blockIdx.x;
  int t = threadIdx.x;
  __shared__ float red[256];
  float vals[3];
  float sum = 0.f;
  #pragma unroll
  for (int i = 0; i < 3; ++i) {
    int d = t + i * 256;
    float val = x[(size_t)n * DMODEL + d];
    if (o) val += o[(size_t)n * DMODEL + d];
    vals[i] = val;
    sum += val;
  }
  red[t] = sum; __syncthreads();
  for (int off = 128; off; off >>= 1) {
    if (t < off) red[t] += red[t + off];
    __syncthreads();
  }
  float mu = red[0] * (1.0f / DMODEL);
  __syncthreads();
  float vs = 0.f;
  #pragma unroll
  for (int i = 0; i < 3; ++i) {
    float dlt = vals[i] - mu;
    vs += dlt * dlt;
  }
  red[t] = vs; __syncthreads();
  for (int off = 128; off; off >>= 1) {
    if (t < off) red[t] += red[t + off];
    __syncthreads();
  }
  float rstd = rsqrtf(red[0] * (1.0f / DMODEL) + 1e-5f);
  __syncthreads();
  #pragma unroll
  for (int i = 0; i < 3; ++i) {
    int d = t + i * 256;
    out[(size_t)n * DMODEL + d] = (vals[i] - mu) * rstd * g[d] + bta[d];
  }
}

// ---------------------------------------------------------------------------
// Mean-pool over sequence: pooled[b,d] = mean_s xin[b,s,d]
// ---------------------------------------------------------------------------
__global__ __launch_bounds__(256) void pool_kernel(
    const float* __restrict__ xin, float* __restrict__ pooled) {
  int blk = blockIdx.x;
  int b = blk / (DMODEL / 256);
  int dc = blk % (DMODEL / 256);
  int d = dc * 256 + threadIdx.x;
  float s_ = 0.f;
  for (int s = 0; s < SEQ; ++s)
    s_ += xin[(size_t)(b * SEQ + s) * DMODEL + d];
  pooled[b * DMODEL + d] = s_ * (1.0f / SEQ);
}

// ---------------------------------------------------------------------------
// Classifier: logits = pooled @ Wfc + bfc; out = log_softmax(logits)
// ---------------------------------------------------------------------------
__global__ __launch_bounds__(256) void classifier_kernel(
    const float* __restrict__ pooled, const float* __restrict__ Wfc,
    const float* __restrict__ bfc, float* __restrict__ out) {
  int b = blockIdx.x;
  int t = threadIdx.x;
  __shared__ float s0[256], s1[256];
  float acc0 = 0.f, acc1 = 0.f;
  for (int d = t; d < DMODEL; d += 256) {
    float p = pooled[b * DMODEL + d];
    acc0 += p * Wfc[d * NCLS + 0];
    acc1 += p * Wfc[d * NCLS + 1];
  }
  s0[t] = acc0; s1[t] = acc1; __syncthreads();
  for (int off = 128; off; off >>= 1) {
    if (t < off) { s0[t] += s0[t + off]; s1[t] += s1[t + off]; }
    __syncthreads();
  }
  if (t == 0) {
    float l0 = s0[0] + bfc[0], l1 = s1[0] + bfc[1];
    float m = fmaxf(l0, l1);
    float lse = m + logf(expf(l0 - m) + expf(l1 - m));
    out[b * NCLS + 0] = l0 - lse;
    out[b * NCLS + 1] = l1 - lse;
  }
}

// ---------------------------------------------------------------------------
extern "C" void kernel_launch(void* const* d_in, const int* in_sizes, int n_in,
                              void* d_out, int out_size, void* d_ws, size_t ws_size,
                              hipStream_t stream) {
  const int*   text  = (const int*)d_in[0];
  const int*   mask  = (const int*)d_in[1];
  const float* emb   = (const float*)d_in[2];
  const float* Wq    = (const float*)d_in[3];
  const float* bq    = (const float*)d_in[4];
  const float* Wk    = (const float*)d_in[5];
  const float* bk    = (const float*)d_in[6];
  const float* Wv    = (const float*)d_in[7];
  const float* bv    = (const float*)d_in[8];
  const float* Wo    = (const float*)d_in[9];
  const float* bo    = (const float*)d_in[10];
  const float* W1    = (const float*)d_in[11];
  const float* b1    = (const float*)d_in[12];
  const float* W2    = (const float*)d_in[13];
  const float* b2    = (const float*)d_in[14];
  const float* ln1_g = (const float*)d_in[15];
  const float* ln1_b = (const float*)d_in[16];
  const float* ln2_g = (const float*)d_in[17];
  const float* ln2_b = (const float*)d_in[18];
  const float* lnf_g = (const float*)d_in[19];
  const float* lnf_b = (const float*)d_in[20];
  const float* Wfc   = (const float*)d_in[21];
  const float* bfc   = (const float*)d_in[22];

  const size_t ND = (size_t)NTOK * DMODEL;   // 3,145,728
  const size_t NF = (size_t)NTOK * FFDIM;    // 12,582,912
  float* ws = (float*)d_ws;
  float* x      = ws;            // [N,D]
  float* q      = x + ND;        // [N,D]  (also o-proj / ffn2 output)
  float* kbuf   = q + ND;        // [N,D]
  float* vbuf   = kbuf + ND;     // [N,D]
  float* h1     = vbuf + ND;     // [N,FF]; attention output aliased here
  float* ao     = h1;            //   (dead when FFN1 runs)
  float* pooled = h1 + NF;       // [B,D]

  dim3 blk2(16, 16);
  dim3 gD(DMODEL / 64, NTOK / 64);   // N-out = 768
  dim3 gF(FFDIM / 64, NTOK / 64);    // N-out = 3072

  embed_kernel<<<NTOK, 256, 0, stream>>>(text, emb, x);

  for (int l = 0; l < LAYERS; ++l) {
    const float* wq = Wq + (size_t)l * DMODEL * DMODEL;
    const float* wk = Wk + (size_t)l * DMODEL * DMODEL;
    const float* wv = Wv + (size_t)l * DMODEL * DMODEL;
    const float* wo = Wo + (size_t)l * DMODEL * DMODEL;
    const float* w1 = W1 + (size_t)l * DMODEL * FFDIM;
    const float* w2 = W2 + (size_t)l * FFDIM * DMODEL;

    gemm_bias_kernel<<<gD, blk2, 0, stream>>>(x, wq, bq + l * DMODEL, q,    NTOK, DMODEL, DMODEL, 0);
    gemm_bias_kernel<<<gD, blk2, 0, stream>>>(x, wk, bk + l * DMODEL, kbuf, NTOK, DMODEL, DMODEL, 0);
    gemm_bias_kernel<<<gD, blk2, 0, stream>>>(x, wv, bv + l * DMODEL, vbuf, NTOK, DMODEL, DMODEL, 0);

    attention_tiled_kernel<<<BATCH * NHEAD * (SEQ / QT), 256, 0, stream>>>(q, kbuf, vbuf, mask, ao);

    // o-projection into q (q dead now)
    gemm_bias_kernel<<<gD, blk2, 0, stream>>>(ao, wo, bo + l * DMODEL, q, NTOK, DMODEL, DMODEL, 0);
    // x = LN(x + o)
    ln_kernel<<<NTOK, 256, 0, stream>>>(x, q, x, ln1_g + l * DMODEL, ln1_b + l * DMODEL);
    // ffn
    gemm_bias_kernel<<<gF, blk2, 0, stream>>>(x, w1, b1 + l * FFDIM, h1, NTOK, DMODEL, FFDIM, 1);
    gemm_bias_kernel<<<gD, blk2, 0, stream>>>(h1, w2, b2 + l * DMODEL, q, NTOK, FFDIM, DMODEL, 0);
    // x = LN(x + ffn)
    ln_kernel<<<NTOK, 256, 0, stream>>>(x, q, x, ln2_g + l * DMODEL, ln2_b + l * DMODEL);
  }

  // final LN into q, pool, classify
  ln_kernel<<<NTOK, 256, 0, stream>>>(x, nullptr, q, lnf_g, lnf_b);
  pool_kernel<<<BATCH * (DMODEL / 256), 256, 0, stream>>>(q, pooled);
  classifier_kernel<<<BATCH, 256, 0, stream>>>(pooled, Wfc, bfc, (float*)d_out);
}

// Round 3
// 1342.986 us; speedup vs baseline: 7.5958x; 2.9651x over previous
//
#include <hip/hip_runtime.h>
#include <hip/hip_bf16.h>
#include <math.h>

// Problem constants (match reference)
#define LAYERS 4
#define DMODEL 768
#define NHEAD 12
#define HDIM 64
#define FFDIM 3072
#define VOCAB 32000
#define NCLS 2
#define BATCH 8
#define SEQ 512
#define NTOK (BATCH * SEQ)   // 4096

typedef __attribute__((ext_vector_type(8))) short short8;      // 8 bf16 (4 VGPR)
typedef __attribute__((ext_vector_type(8))) unsigned short ushortx8;
typedef __attribute__((ext_vector_type(4))) float f32x4;

__device__ __forceinline__ float bf2f(unsigned short u) {
  return __uint_as_float(((unsigned)u) << 16);
}
__device__ __forceinline__ unsigned short f2bf(float x) {
  unsigned u = __float_as_uint(x);
  unsigned r = (u + 0x7fffu + ((u >> 16) & 1u)) >> 16;   // RNE
  return (unsigned short)r;
}

// async global->LDS, 16 bytes per lane (wave-uniform LDS base + lane*16)
__device__ __forceinline__ void gload16(const void* gp, void* lp) {
  __builtin_amdgcn_global_load_lds(
      (const __attribute__((address_space(1))) void*)((unsigned long long)gp),
      (__attribute__((address_space(3))) void*)((unsigned int)(unsigned long long)lp),
      16, 0, 0);
}

// ---------------------------------------------------------------------------
// Embedding + positional encoding; writes f32 x (residual) and bf16 xb (GEMM in)
// ---------------------------------------------------------------------------
__global__ __launch_bounds__(256) void embed_kernel(
    const int* __restrict__ text, const float* __restrict__ emb,
    float* __restrict__ x, unsigned short* __restrict__ xb) {
  int n = blockIdx.x;
  int t = threadIdx.x;
  int tok = text[n];
  int s = n % SEQ;
  const float sqrtD = 27.712812921102035f;
  const float nlog10k_over_d = -9.210340371976184f / 768.0f;
  #pragma unroll
  for (int i = 0; i < 3; ++i) {
    int d = t + i * 256;
    int j = d >> 1;
    float freq = expf((float)(2 * j) * nlog10k_over_d);
    float ang = (float)s * freq;
    float pe = (d & 1) ? cosf(ang) : sinf(ang);
    float val = emb[(size_t)tok * DMODEL + d] * sqrtD + pe;
    x[(size_t)n * DMODEL + d] = val;
    xb[(size_t)n * DMODEL + d] = f2bf(val);
  }
}

// ---------------------------------------------------------------------------
// Weight convert+transpose: W[K][N] f32 -> Wt[N][K] bf16. grid=(N/64, K/64)
// ---------------------------------------------------------------------------
__global__ __launch_bounds__(256) void wconv_kernel(
    const float* __restrict__ W, unsigned short* __restrict__ Wt,
    int K, int N) {
  __shared__ float t[64][65];
  int k0 = blockIdx.y * 64, n0 = blockIdx.x * 64;
  int tid = threadIdx.x;
  {
    int r = tid >> 2, c4 = (tid & 3) * 16;
    #pragma unroll
    for (int j = 0; j < 4; ++j) {
      float4 vv = *(const float4*)(W + (size_t)(k0 + r) * N + n0 + c4 + j * 4);
      t[r][c4 + j * 4 + 0] = vv.x; t[r][c4 + j * 4 + 1] = vv.y;
      t[r][c4 + j * 4 + 2] = vv.z; t[r][c4 + j * 4 + 3] = vv.w;
    }
  }
  __syncthreads();
  {
    int n = tid >> 2, k4 = (tid & 3) * 16;
    ushortx8 u0, u1;
    #pragma unroll
    for (int j = 0; j < 8; ++j) u0[j] = f2bf(t[k4 + j][n]);
    #pragma unroll
    for (int j = 0; j < 8; ++j) u1[j] = f2bf(t[k4 + 8 + j][n]);
    *(ushortx8*)(Wt + (size_t)(n0 + n) * K + k0 + k4) = u0;
    *(ushortx8*)(Wt + (size_t)(n0 + n) * K + k0 + k4 + 8) = u1;
  }
}

// ---------------------------------------------------------------------------
// bf16 MFMA GEMM: C[M][N] = A[M][K] @ Wt[N][K]^T + bias
// 128x128 tile, BK=64, 4 waves (2x2), 4x4 16x16x32 fragments per wave.
// XOR-swizzled LDS (k-group ^= row&7) staged via pre-swizzled global addrs.
// ---------------------------------------------------------------------------
#define BM 128
#define BN 128
#define BK 64
__global__ __launch_bounds__(256, 2) void gemm_mfma_kernel(
    const unsigned short* __restrict__ A,    // [M][K] bf16
    const unsigned short* __restrict__ Bt,   // [N][K] bf16
    const float* __restrict__ bias,          // [N] f32
    void* __restrict__ Cout,                 // [M][N] f32 or bf16
    int M, int N, int K, int out_bf16, int relu) {
  __shared__ unsigned short As[BM * BK];     // swizzled [row][kgrp^...]
  __shared__ unsigned short Bs[BN * BK];

  const int tid = threadIdx.x;
  const int lane = tid & 63;
  const int wave = tid >> 6;
  const int m0 = blockIdx.y * BM;
  const int n0 = blockIdx.x * BN;
  const int wrow = (wave >> 1) * 64;
  const int wcol = (wave & 1) * 64;

  // staging: wave handles rows [32*wave, 32*wave+32) in 4 chunks of 8 rows
  const int lrow = lane >> 3;                 // 0..7
  const int kgrp = (lane & 7) ^ lrow;         // swizzled k-group to fetch

  const unsigned short* Ab = A  + (size_t)(m0 + 32 * wave + lrow) * K + kgrp * 8;
  const unsigned short* Bb = Bt + (size_t)(n0 + 32 * wave + lrow) * K + kgrp * 8;
  unsigned short* AsW = As + wave * 2048 + lane * 8;   // elements
  unsigned short* BsW = Bs + wave * 2048 + lane * 8;

  f32x4 acc[4][4];
  #pragma unroll
  for (int m = 0; m < 4; ++m)
    #pragma unroll
    for (int n = 0; n < 4; ++n)
      acc[m][n] = (f32x4){0.f, 0.f, 0.f, 0.f};

  const int g0 = (lane >> 4) ^ (lane & 7);   // k-group for kh=0 frag read

  for (int k0 = 0; k0 < K; k0 += BK) {
    __syncthreads();
    #pragma unroll
    for (int i = 0; i < 4; ++i) {
      gload16(Ab + (size_t)(8 * i) * K + k0, AsW + i * 512);
      gload16(Bb + (size_t)(8 * i) * K + k0, BsW + i * 512);
    }
    __syncthreads();
    #pragma unroll
    for (int kh = 0; kh < 2; ++kh) {
      const int gs = g0 ^ (kh * 4);
      short8 a[4], b[4];
      #pragma unroll
      for (int m = 0; m < 4; ++m) {
        int r = wrow + m * 16 + (lane & 15);
        a[m] = *(const short8*)(As + r * 64 + gs * 8);
      }
      #pragma unroll
      for (int n = 0; n < 4; ++n) {
        int r = wcol + n * 16 + (lane & 15);
        b[n] = *(const short8*)(Bs + r * 64 + gs * 8);
      }
      #pragma unroll
      for (int m = 0; m < 4; ++m)
        #pragma unroll
        for (int n = 0; n < 4; ++n)
          acc[m][n] = __builtin_amdgcn_mfma_f32_16x16x32_bf16(a[m], b[n], acc[m][n], 0, 0, 0);
    }
  }

  // epilogue: D row = (lane>>4)*4 + reg, col = lane&15 (per-fragment)
  const int crow0 = m0 + wrow + (lane >> 4) * 4;
  const int ccol0 = n0 + wcol + (lane & 15);
  #pragma unroll
  for (int n = 0; n < 4; ++n) {
    float bv = bias[ccol0 + n * 16];
    #pragma unroll
    for (int m = 0; m < 4; ++m) {
      #pragma unroll
      for (int r = 0; r < 4; ++r) {
        float val = acc[m][n][r] + bv;
        if (relu) val = fmaxf(val, 0.f);
        size_t idx = (size_t)(crow0 + m * 16 + r) * N + ccol0 + n * 16;
        if (out_bf16) ((unsigned short*)Cout)[idx] = f2bf(val);
        else          ((float*)Cout)[idx] = val;
      }
    }
  }
}

// ---------------------------------------------------------------------------
// Tiled flash-style attention (bf16 in, bf16 out), f32 math inside.
// One block per (b, h, 64-query tile), 256 threads (16x16), 4x4 microtiles.
// ---------------------------------------------------------------------------
#define QT 64
#define KT 64
__global__ __launch_bounds__(256) void attention_tiled_kernel(
    const unsigned short* __restrict__ q, const unsigned short* __restrict__ k,
    const unsigned short* __restrict__ v, const int* __restrict__ mask,
    unsigned short* __restrict__ out) {
  int blk = blockIdx.x;
  int qt0 = (blk % (SEQ / QT)) * QT;
  int h = (blk / (SEQ / QT)) % NHEAD;
  int b = blk / ((SEQ / QT) * NHEAD);

  __shared__ float qs[HDIM][68];   // [dim][query]
  __shared__ float ks[HDIM][68];   // [dim][key]
  __shared__ float vs[KT][68];     // [key][dim]
  __shared__ float ps[KT][65];     // [key][query]
  __shared__ float m_s[QT], l_s[QT], corr_s[QT];

  int tid = threadIdx.x;
  int tx = tid & 15, ty = tid >> 4;
  const size_t headoff = (size_t)h * HDIM;

  // ---- load Q tile transposed (bf16 -> f32) ----
  #pragma unroll
  for (int it = 0; it < 2; ++it) {
    int r = (tid >> 3) + it * 32;
    int c0 = (tid & 7) * 8;
    ushortx8 qv = *(const ushortx8*)(q + (size_t)(b * SEQ + qt0 + r) * DMODEL + headoff + c0);
    #pragma unroll
    for (int j = 0; j < 8; ++j) qs[c0 + j][r] = bf2f(qv[j]);
  }
  if (tid < QT) { m_s[tid] = -3.0e38f; l_s[tid] = 0.0f; }

  float o[4][4] = {};

  for (int kt = 0; kt < SEQ / KT; ++kt) {
    __syncthreads();
    #pragma unroll
    for (int it = 0; it < 2; ++it) {
      int r = (tid >> 3) + it * 32;
      int c0 = (tid & 7) * 8;
      ushortx8 kv = *(const ushortx8*)(k + (size_t)(b * SEQ + kt * KT + r) * DMODEL + headoff + c0);
      ushortx8 vv = *(const ushortx8*)(v + (size_t)(b * SEQ + kt * KT + r) * DMODEL + headoff + c0);
      #pragma unroll
      for (int j = 0; j < 8; ++j) {
        ks[c0 + j][r] = bf2f(kv[j]);
        vs[r][c0 + j] = bf2f(vv[j]);
      }
    }
    __syncthreads();

    // ---- S = Q K^T / 8 (+mask), stored transposed ps[key][query] ----
    {
      float s[4][4] = {};
      #pragma unroll 16
      for (int kk = 0; kk < HDIM; ++kk) {
        float a4[4], w4[4];
        *(float4*)a4 = *(const float4*)&qs[kk][ty * 4];
        *(float4*)w4 = *(const float4*)&ks[kk][tx * 4];
        #pragma unroll
        for (int i = 0; i < 4; ++i)
          #pragma unroll
          for (int j = 0; j < 4; ++j)
            s[i][j] += a4[i] * w4[j];
      }
      #pragma unroll
      for (int j = 0; j < 4; ++j) {
        int key = kt * KT + tx * 4 + j;
        int msk = mask[b * SEQ + key];
        #pragma unroll
        for (int i = 0; i < 4; ++i) {
          float val = s[i][j] * 0.125f;
          if (msk == 0) val = -1e9f;
          ps[tx * 4 + j][ty * 4 + i] = val;
        }
      }
    }
    __syncthreads();

    // ---- online softmax: 4 threads per query ----
    {
      int qq = tid >> 2;
      int part = tid & 3;
      float mp = -3.0e38f;
      #pragma unroll
      for (int kk = part * 16; kk < part * 16 + 16; ++kk)
        mp = fmaxf(mp, ps[kk][qq]);
      mp = fmaxf(mp, __shfl_xor(mp, 1));
      mp = fmaxf(mp, __shfl_xor(mp, 2));
      float m_old = m_s[qq];
      float m_new = fmaxf(m_old, mp);
      float sp = 0.f;
      #pragma unroll
      for (int kk = part * 16; kk < part * 16 + 16; ++kk) {
        float e = expf(ps[kk][qq] - m_new);
        ps[kk][qq] = e;
        sp += e;
      }
      sp += __shfl_xor(sp, 1);
      sp += __shfl_xor(sp, 2);
      if (part == 0) {
        float corr = expf(m_old - m_new);
        m_s[qq] = m_new;
        l_s[qq] = l_s[qq] * corr + sp;
        corr_s[qq] = corr;
      }
    }
    __syncthreads();

    // ---- O = O*corr + P V ----
    {
      #pragma unroll
      for (int i = 0; i < 4; ++i) {
        float c = corr_s[ty * 4 + i];
        #pragma unroll
        for (int j = 0; j < 4; ++j) o[i][j] *= c;
      }
      #pragma unroll 8
      for (int kk = 0; kk < KT; ++kk) {
        float w4[4];
        *(float4*)w4 = *(const float4*)&vs[kk][tx * 4];
        float a0 = ps[kk][ty * 4 + 0];
        float a1 = ps[kk][ty * 4 + 1];
        float a2 = ps[kk][ty * 4 + 2];
        float a3 = ps[kk][ty * 4 + 3];
        #pragma unroll
        for (int j = 0; j < 4; ++j) {
          o[0][j] += a0 * w4[j];
          o[1][j] += a1 * w4[j];
          o[2][j] += a2 * w4[j];
          o[3][j] += a3 * w4[j];
        }
      }
    }
  }
  __syncthreads();

  typedef __attribute__((ext_vector_type(4))) unsigned short ushortx4;
  #pragma unroll
  for (int i = 0; i < 4; ++i) {
    int qq = ty * 4 + i;
    float inv = 1.0f / l_s[qq];
    ushortx4 r;
    r[0] = f2bf(o[i][0] * inv); r[1] = f2bf(o[i][1] * inv);
    r[2] = f2bf(o[i][2] * inv); r[3] = f2bf(o[i][3] * inv);
    *(ushortx4*)(out + (size_t)(b * SEQ + qt0 + qq) * DMODEL + headoff + tx * 4) = r;
  }
}

// ---------------------------------------------------------------------------
// LayerNorm (+optional residual); writes f32 out and optional bf16 outb.
// ---------------------------------------------------------------------------
__global__ __launch_bounds__(256) void ln_kernel(
    const float* __restrict__ x, const float* __restrict__ o,
    float* __restrict__ out, unsigned short* __restrict__ outb,
    const float* __restrict__ g, const float* __restrict__ bta) {
  int n = blockIdx.x;
  int t = threadIdx.x;
  __shared__ float red[256];
  float vals[3];
  float sum = 0.f;
  #pragma unroll
  for (int i = 0; i < 3; ++i) {
    int d = t + i * 256;
    float val = x[(size_t)n * DMODEL + d];
    if (o) val += o[(size_t)n * DMODEL + d];
    vals[i] = val;
    sum += val;
  }
  red[t] = sum; __syncthreads();
  for (int off = 128; off; off >>= 1) {
    if (t < off) red[t] += red[t + off];
    __syncthreads();
  }
  float mu = red[0] * (1.0f / DMODEL);
  __syncthreads();
  float vs = 0.f;
  #pragma unroll
  for (int i = 0; i < 3; ++i) {
    float dlt = vals[i] - mu;
    vs += dlt * dlt;
  }
  red[t] = vs; __syncthreads();
  for (int off = 128; off; off >>= 1) {
    if (t < off) red[t] += red[t + off];
    __syncthreads();
  }
  float rstd = rsqrtf(red[0] * (1.0f / DMODEL) + 1e-5f);
  __syncthreads();
  #pragma unroll
  for (int i = 0; i < 3; ++i) {
    int d = t + i * 256;
    float val = (vals[i] - mu) * rstd * g[d] + bta[d];
    out[(size_t)n * DMODEL + d] = val;
    if (outb) outb[(size_t)n * DMODEL + d] = f2bf(val);
  }
}

// ---------------------------------------------------------------------------
__global__ __launch_bounds__(256) void pool_kernel(
    const float* __restrict__ xin, float* __restrict__ pooled) {
  int blk = blockIdx.x;
  int b = blk / (DMODEL / 256);
  int dc = blk % (DMODEL / 256);
  int d = dc * 256 + threadIdx.x;
  float s_ = 0.f;
  for (int s = 0; s < SEQ; ++s)
    s_ += xin[(size_t)(b * SEQ + s) * DMODEL + d];
  pooled[b * DMODEL + d] = s_ * (1.0f / SEQ);
}

__global__ __launch_bounds__(256) void classifier_kernel(
    const float* __restrict__ pooled, const float* __restrict__ Wfc,
    const float* __restrict__ bfc, float* __restrict__ out) {
  int b = blockIdx.x;
  int t = threadIdx.x;
  __shared__ float s0[256], s1[256];
  float acc0 = 0.f, acc1 = 0.f;
  for (int d = t; d < DMODEL; d += 256) {
    float p = pooled[b * DMODEL + d];
    acc0 += p * Wfc[d * NCLS + 0];
    acc1 += p * Wfc[d * NCLS + 1];
  }
  s0[t] = acc0; s1[t] = acc1; __syncthreads();
  for (int off = 128; off; off >>= 1) {
    if (t < off) { s0[t] += s0[t + off]; s1[t] += s1[t + off]; }
    __syncthreads();
  }
  if (t == 0) {
    float l0 = s0[0] + bfc[0], l1 = s1[0] + bfc[1];
    float m = fmaxf(l0, l1);
    float lse = m + logf(expf(l0 - m) + expf(l1 - m));
    out[b * NCLS + 0] = l0 - lse;
    out[b * NCLS + 1] = l1 - lse;
  }
}

// ---------------------------------------------------------------------------
extern "C" void kernel_launch(void* const* d_in, const int* in_sizes, int n_in,
                              void* d_out, int out_size, void* d_ws, size_t ws_size,
                              hipStream_t stream) {
  const int*   text  = (const int*)d_in[0];
  const int*   mask  = (const int*)d_in[1];
  const float* emb   = (const float*)d_in[2];
  const float* Wq    = (const float*)d_in[3];
  const float* bq    = (const float*)d_in[4];
  const float* Wk    = (const float*)d_in[5];
  const float* bk    = (const float*)d_in[6];
  const float* Wv    = (const float*)d_in[7];
  const float* bv    = (const float*)d_in[8];
  const float* Wo    = (const float*)d_in[9];
  const float* bo    = (const float*)d_in[10];
  const float* W1    = (const float*)d_in[11];
  const float* b1    = (const float*)d_in[12];
  const float* W2    = (const float*)d_in[13];
  const float* b2    = (const float*)d_in[14];
  const float* ln1_g = (const float*)d_in[15];
  const float* ln1_b = (const float*)d_in[16];
  const float* ln2_g = (const float*)d_in[17];
  const float* ln2_b = (const float*)d_in[18];
  const float* lnf_g = (const float*)d_in[19];
  const float* lnf_b = (const float*)d_in[20];
  const float* Wfc   = (const float*)d_in[21];
  const float* bfc   = (const float*)d_in[22];

  const size_t ND = (size_t)NTOK * DMODEL;
  const size_t NF = (size_t)NTOK * FFDIM;
  const size_t WDD = (size_t)DMODEL * DMODEL;    // 589824
  const size_t WDF = (size_t)DMODEL * FFDIM;     // 2359296

  float* xf     = (float*)d_ws;                  // [N,D] f32 residual
  float* of     = xf + ND;                       // [N,D] f32 (proj/ffn2/finalLN out)
  float* pooled = of + ND;                       // [B,D]
  unsigned short* xb  = (unsigned short*)(pooled + BATCH * DMODEL);  // [N,D] bf16
  unsigned short* qb  = xb + ND;
  unsigned short* kb  = qb + ND;
  unsigned short* vb  = kb + ND;
  unsigned short* aob = vb + ND;
  unsigned short* h1b = aob + ND;                // [N,FF] bf16
  unsigned short* wtb = h1b + NF;                // per-layer transposed weights
  unsigned short* wqT = wtb;
  unsigned short* wkT = wqT + WDD;
  unsigned short* wvT = wkT + WDD;
  unsigned short* woT = wvT + WDD;
  unsigned short* w1T = woT + WDD;               // [FF][D]
  unsigned short* w2T = w1T + WDF;               // [D][FF]

  dim3 gD(DMODEL / BN, NTOK / BM);   // (6, 32)
  dim3 gF(FFDIM / BN, NTOK / BM);    // (24, 32)

  embed_kernel<<<NTOK, 256, 0, stream>>>(text, emb, xf, xb);

  for (int l = 0; l < LAYERS; ++l) {
    const float* wq = Wq + (size_t)l * WDD;
    const float* wk = Wk + (size_t)l * WDD;
    const float* wv = Wv + (size_t)l * WDD;
    const float* wo = Wo + (size_t)l * WDD;
    const float* w1 = W1 + (size_t)l * WDF;
    const float* w2 = W2 + (size_t)l * WDF;

    wconv_kernel<<<dim3(12, 12), 256, 0, stream>>>(wq, wqT, DMODEL, DMODEL);
    wconv_kernel<<<dim3(12, 12), 256, 0, stream>>>(wk, wkT, DMODEL, DMODEL);
    wconv_kernel<<<dim3(12, 12), 256, 0, stream>>>(wv, wvT, DMODEL, DMODEL);
    wconv_kernel<<<dim3(12, 12), 256, 0, stream>>>(wo, woT, DMODEL, DMODEL);
    wconv_kernel<<<dim3(48, 12), 256, 0, stream>>>(w1, w1T, DMODEL, FFDIM);
    wconv_kernel<<<dim3(12, 48), 256, 0, stream>>>(w2, w2T, FFDIM, DMODEL);

    gemm_mfma_kernel<<<gD, 256, 0, stream>>>(xb, wqT, bq + l * DMODEL, qb, NTOK, DMODEL, DMODEL, 1, 0);
    gemm_mfma_kernel<<<gD, 256, 0, stream>>>(xb, wkT, bk + l * DMODEL, kb, NTOK, DMODEL, DMODEL, 1, 0);
    gemm_mfma_kernel<<<gD, 256, 0, stream>>>(xb, wvT, bv + l * DMODEL, vb, NTOK, DMODEL, DMODEL, 1, 0);

    attention_tiled_kernel<<<BATCH * NHEAD * (SEQ / QT), 256, 0, stream>>>(qb, kb, vb, mask, aob);

    gemm_mfma_kernel<<<gD, 256, 0, stream>>>(aob, woT, bo + l * DMODEL, of, NTOK, DMODEL, DMODEL, 0, 0);
    ln_kernel<<<NTOK, 256, 0, stream>>>(xf, of, xf, xb, ln1_g + l * DMODEL, ln1_b + l * DMODEL);
    gemm_mfma_kernel<<<gF, 256, 0, stream>>>(xb, w1T, b1 + l * FFDIM, h1b, NTOK, FFDIM, DMODEL, 1, 1);
    gemm_mfma_kernel<<<gD, 256, 0, stream>>>(h1b, w2T, b2 + l * DMODEL, of, NTOK, DMODEL, FFDIM, 0, 0);
    ln_kernel<<<NTOK, 256, 0, stream>>>(xf, of, xf, xb, ln2_g + l * DMODEL, ln2_b + l * DMODEL);
  }

  ln_kernel<<<NTOK, 256, 0, stream>>>(xf, nullptr, of, nullptr, lnf_g, lnf_b);
  pool_kernel<<<BATCH * (DMODEL / 256), 256, 0, stream>>>(of, pooled);
  classifier_kernel<<<BATCH, 256, 0, stream>>>(pooled, Wfc, bfc, (float*)d_out);
}

// Round 4
// 900.897 us; speedup vs baseline: 11.3232x; 1.4907x over previous
//
#include <hip/hip_runtime.h>
#include <hip/hip_bf16.h>
#include <math.h>

// Problem constants (match reference)
#define LAYERS 4
#define DMODEL 768
#define NHEAD 12
#define HDIM 64
#define FFDIM 3072
#define VOCAB 32000
#define NCLS 2
#define BATCH 8
#define SEQ 512
#define NTOK (BATCH * SEQ)   // 4096
#define QKVN (3 * DMODEL)    // 2304

typedef __attribute__((ext_vector_type(8))) short short8;      // 8 bf16 (4 VGPR)
typedef __attribute__((ext_vector_type(8))) unsigned short ushortx8;
typedef __attribute__((ext_vector_type(4))) float f32x4;

__device__ __forceinline__ float bf2f(unsigned short u) {
  return __uint_as_float(((unsigned)u) << 16);
}
__device__ __forceinline__ unsigned short f2bf(float x) {
  unsigned u = __float_as_uint(x);
  unsigned r = (u + 0x7fffu + ((u >> 16) & 1u)) >> 16;   // RNE
  return (unsigned short)r;
}

// async global->LDS, 16 bytes per lane (lds ptr = wave-uniform base + lane*16)
__device__ __forceinline__ void gload16(const void* gp, void* lp) {
  __builtin_amdgcn_global_load_lds(
      (const __attribute__((address_space(1))) void*)((unsigned long long)gp),
      (__attribute__((address_space(3))) void*)((unsigned int)(unsigned long long)lp),
      16, 0, 0);
}

// ---------------------------------------------------------------------------
// Embedding + positional encoding; writes f32 x (residual) and bf16 xb
// ---------------------------------------------------------------------------
__global__ __launch_bounds__(256) void embed_kernel(
    const int* __restrict__ text, const float* __restrict__ emb,
    float* __restrict__ x, unsigned short* __restrict__ xb) {
  int n = blockIdx.x;
  int t = threadIdx.x;
  int tok = text[n];
  int s = n % SEQ;
  const float sqrtD = 27.712812921102035f;
  const float nlog10k_over_d = -9.210340371976184f / 768.0f;
  #pragma unroll
  for (int i = 0; i < 3; ++i) {
    int d = t + i * 256;
    int j = d >> 1;
    float freq = expf((float)(2 * j) * nlog10k_over_d);
    float ang = (float)s * freq;
    float pe = (d & 1) ? cosf(ang) : sinf(ang);
    float val = emb[(size_t)tok * DMODEL + d] * sqrtD + pe;
    x[(size_t)n * DMODEL + d] = val;
    xb[(size_t)n * DMODEL + d] = f2bf(val);
  }
}

// ---------------------------------------------------------------------------
// Weight convert+transpose: W[K][N] f32 -> Wt[N][K] bf16. grid=(N/64, K/64)
// ---------------------------------------------------------------------------
__global__ __launch_bounds__(256) void wconv_kernel(
    const float* __restrict__ W, unsigned short* __restrict__ Wt,
    int K, int N) {
  __shared__ float t[64][65];
  int k0 = blockIdx.y * 64, n0 = blockIdx.x * 64;
  int tid = threadIdx.x;
  {
    int r = tid >> 2, c4 = (tid & 3) * 16;
    #pragma unroll
    for (int j = 0; j < 4; ++j) {
      float4 vv = *(const float4*)(W + (size_t)(k0 + r) * N + n0 + c4 + j * 4);
      t[r][c4 + j * 4 + 0] = vv.x; t[r][c4 + j * 4 + 1] = vv.y;
      t[r][c4 + j * 4 + 2] = vv.z; t[r][c4 + j * 4 + 3] = vv.w;
    }
  }
  __syncthreads();
  {
    int n = tid >> 2, k4 = (tid & 3) * 16;
    ushortx8 u0, u1;
    #pragma unroll
    for (int j = 0; j < 8; ++j) u0[j] = f2bf(t[k4 + j][n]);
    #pragma unroll
    for (int j = 0; j < 8; ++j) u1[j] = f2bf(t[k4 + 8 + j][n]);
    *(ushortx8*)(Wt + (size_t)(n0 + n) * K + k0 + k4) = u0;
    *(ushortx8*)(Wt + (size_t)(n0 + n) * K + k0 + k4 + 8) = u1;
  }
}

// ---------------------------------------------------------------------------
// bf16 MFMA GEMM: C[M][N] = A[M][K] @ Bt[N][K]^T + bias
// 128x128 tile, BK=64, 4 waves, 4x4 16x16x32 fragments per wave.
// Optional QKV mode (vTout != null, N=2304): bias from 3 regions; cols>=1536
// (the V projection) are written transposed to vTout[(b*H+h)*64+d][s].
// ---------------------------------------------------------------------------
#define BM 128
#define BN 128
#define BK 64
__global__ __launch_bounds__(256, 2) void gemm_mfma_kernel(
    const unsigned short* __restrict__ A,    // [M][K] bf16
    const unsigned short* __restrict__ Bt,   // [N][K] bf16
    const float* __restrict__ bias,          // [N] (or Q region)
    const float* __restrict__ biasK,         // K region (QKV mode)
    const float* __restrict__ biasV,         // V region (QKV mode)
    void* __restrict__ Cout,                 // [M][N] f32 or bf16
    unsigned short* __restrict__ vTout,      // QKV mode V^T output
    int M, int N, int K, int out_bf16, int relu) {
  __shared__ unsigned short As[BM * BK];
  __shared__ unsigned short Bs[BN * BK];

  const int tid = threadIdx.x;
  const int lane = tid & 63;
  const int wave = tid >> 6;
  const int m0 = blockIdx.y * BM;
  const int n0 = blockIdx.x * BN;
  const int wrow = (wave >> 1) * 64;
  const int wcol = (wave & 1) * 64;

  const int lrow = lane >> 3;
  const int kgrp = (lane & 7) ^ lrow;

  const unsigned short* Ab = A  + (size_t)(m0 + 32 * wave + lrow) * K + kgrp * 8;
  const unsigned short* Bb = Bt + (size_t)(n0 + 32 * wave + lrow) * K + kgrp * 8;
  unsigned short* AsW = As + wave * 2048 + lane * 8;
  unsigned short* BsW = Bs + wave * 2048 + lane * 8;

  f32x4 acc[4][4];
  #pragma unroll
  for (int m = 0; m < 4; ++m)
    #pragma unroll
    for (int n = 0; n < 4; ++n)
      acc[m][n] = (f32x4){0.f, 0.f, 0.f, 0.f};

  const int g0 = (lane >> 4) ^ (lane & 7);

  for (int k0 = 0; k0 < K; k0 += BK) {
    __syncthreads();
    #pragma unroll
    for (int i = 0; i < 4; ++i) {
      gload16(Ab + (size_t)(8 * i) * K + k0, AsW + i * 512);
      gload16(Bb + (size_t)(8 * i) * K + k0, BsW + i * 512);
    }
    __syncthreads();
    #pragma unroll
    for (int kh = 0; kh < 2; ++kh) {
      const int gs = g0 ^ (kh * 4);
      short8 a[4], b[4];
      #pragma unroll
      for (int m = 0; m < 4; ++m) {
        int r = wrow + m * 16 + (lane & 15);
        a[m] = *(const short8*)(As + r * 64 + gs * 8);
      }
      #pragma unroll
      for (int n = 0; n < 4; ++n) {
        int r = wcol + n * 16 + (lane & 15);
        b[n] = *(const short8*)(Bs + r * 64 + gs * 8);
      }
      #pragma unroll
      for (int m = 0; m < 4; ++m)
        #pragma unroll
        for (int n = 0; n < 4; ++n)
          acc[m][n] = __builtin_amdgcn_mfma_f32_16x16x32_bf16(a[m], b[n], acc[m][n], 0, 0, 0);
    }
  }

  const int crow0 = m0 + wrow + (lane >> 4) * 4;
  const int ccol0 = n0 + wcol + (lane & 15);
  #pragma unroll
  for (int n = 0; n < 4; ++n) {
    int c = ccol0 + n * 16;
    float bv;
    if (vTout) bv = (c < DMODEL) ? bias[c]
                  : (c < 2 * DMODEL) ? biasK[c - DMODEL] : biasV[c - 2 * DMODEL];
    else bv = bias[c];
    bool tovT = (vTout != nullptr) && (c >= 2 * DMODEL);
    int hd = c - 2 * DMODEL;   // h*64+d when tovT
    #pragma unroll
    for (int m = 0; m < 4; ++m) {
      #pragma unroll
      for (int r = 0; r < 4; ++r) {
        float val = acc[m][n][r] + bv;
        if (relu) val = fmaxf(val, 0.f);
        int mr = crow0 + m * 16 + r;
        if (tovT) {
          vTout[((size_t)((mr >> 9) * NHEAD + (hd >> 6)) * HDIM + (hd & 63)) * SEQ + (mr & 511)] = f2bf(val);
        } else if (out_bf16) {
          ((unsigned short*)Cout)[(size_t)mr * N + c] = f2bf(val);
        } else {
          ((float*)Cout)[(size_t)mr * N + c] = val;
        }
      }
    }
  }
}

// ---------------------------------------------------------------------------
// MFMA flash attention: one block per (b, h, 64-query tile); 4 waves.
// Wave owns 16 q-rows. Q in registers; K from qkv (XOR-swizzled LDS via
// global_load_lds); V from pre-transposed vT (same staging as K).
// Softmax wave-parallel on MFMA C-layout; P round-trips LDS as bf16.
// ---------------------------------------------------------------------------
__global__ __launch_bounds__(256) void attention_mfma_kernel(
    const unsigned short* __restrict__ qkv,  // [NTOK][2304] bf16 (Q|K|V)
    const unsigned short* __restrict__ vT,   // [(b*H+h)*64+d][SEQ] bf16
    const int* __restrict__ mask,            // [B][SEQ]
    unsigned short* __restrict__ out) {      // [NTOK][768] bf16
  int blk = blockIdx.x;
  int qt0 = (blk % (SEQ / 64)) * 64;
  int h = (blk / (SEQ / 64)) % NHEAD;
  int b = blk / ((SEQ / 64) * NHEAD);
  int tid = threadIdx.x, lane = tid & 63, wave = tid >> 6;

  __shared__ unsigned short Ks[64 * 64];     // swizzled [key][dimgrp ^ (key&7)]
  __shared__ unsigned short Vs[64 * 64];     // swizzled [d][keygrp ^ (d&7)]
  __shared__ unsigned short Ps[4][16 * 72];  // per-wave P, stride 72 bf16
  __shared__ int msk_s[SEQ];

  if (tid < SEQ / 4) *(int4*)&msk_s[tid * 4] = *(const int4*)&mask[b * SEQ + tid * 4];

  // Q A-fragments (row = lane&15 within wave's 16 rows; k = (lane>>4)*8 + kc*32)
  int qrow = qt0 + wave * 16 + (lane & 15);
  const unsigned short* qp = qkv + (size_t)(b * SEQ + qrow) * QKVN + h * HDIM + (lane >> 4) * 8;
  short8 qf0 = *(const short8*)qp;
  short8 qf1 = *(const short8*)(qp + 32);

  float m_r[4], l_r[4];
  f32x4 acc_o[4];
  #pragma unroll
  for (int r = 0; r < 4; ++r) { m_r[r] = -3.0e38f; l_r[r] = 0.f; }
  #pragma unroll
  for (int n = 0; n < 4; ++n) acc_o[n] = (f32x4){0.f, 0.f, 0.f, 0.f};

  for (int kt = 0; kt < SEQ / 64; ++kt) {
    __syncthreads();
    // stage K tile and V tile (pre-swizzled global src, linear LDS dest)
    #pragma unroll
    for (int it = 0; it < 2; ++it) {
      int ck = it * 256 + tid;
      int row = ck >> 3, g = ck & 7;
      gload16(qkv + (size_t)(b * SEQ + kt * 64 + row) * QKVN + DMODEL + h * HDIM + ((g ^ (row & 7)) * 8),
              Ks + ck * 8);
      gload16(vT + (size_t)((b * NHEAD + h) * HDIM + row) * SEQ + kt * 64 + ((g ^ (row & 7)) * 8),
              Vs + ck * 8);
    }
    __syncthreads();

    // ---- S = Q K^T ----
    f32x4 acc_s[4];
    #pragma unroll
    for (int n = 0; n < 4; ++n) acc_s[n] = (f32x4){0.f, 0.f, 0.f, 0.f};
    #pragma unroll
    for (int n = 0; n < 4; ++n) {
      int rb = n * 16 + (lane & 15);
      int gq = lane >> 4;
      short8 kf0 = *(const short8*)(Ks + rb * 64 + ((gq ^ (rb & 7)) * 8));
      short8 kf1 = *(const short8*)(Ks + rb * 64 + (((gq + 4) ^ (rb & 7)) * 8));
      acc_s[n] = __builtin_amdgcn_mfma_f32_16x16x32_bf16(qf0, kf0, acc_s[n], 0, 0, 0);
      acc_s[n] = __builtin_amdgcn_mfma_f32_16x16x32_bf16(qf1, kf1, acc_s[n], 0, 0, 0);
    }

    // ---- online softmax (rows r; keys spread over lane&15 x 4 fragments) ----
    float pv[4][4], rmax[4];
    #pragma unroll
    for (int r = 0; r < 4; ++r) rmax[r] = -3.0e38f;
    #pragma unroll
    for (int n = 0; n < 4; ++n) {
      int msk = msk_s[kt * 64 + n * 16 + (lane & 15)];
      #pragma unroll
      for (int r = 0; r < 4; ++r) {
        float s = acc_s[n][r] * 0.125f;
        if (msk == 0) s = -1e9f;
        pv[n][r] = s;
        rmax[r] = fmaxf(rmax[r], s);
      }
    }
    #pragma unroll
    for (int r = 0; r < 4; ++r) {
      rmax[r] = fmaxf(rmax[r], __shfl_xor(rmax[r], 1));
      rmax[r] = fmaxf(rmax[r], __shfl_xor(rmax[r], 2));
      rmax[r] = fmaxf(rmax[r], __shfl_xor(rmax[r], 4));
      rmax[r] = fmaxf(rmax[r], __shfl_xor(rmax[r], 8));
    }
    float corr[4], psum[4];
    #pragma unroll
    for (int r = 0; r < 4; ++r) {
      float mn = fmaxf(m_r[r], rmax[r]);
      corr[r] = expf(m_r[r] - mn);
      m_r[r] = mn;
      psum[r] = 0.f;
    }
    #pragma unroll
    for (int n = 0; n < 4; ++n) {
      #pragma unroll
      for (int r = 0; r < 4; ++r) {
        float e = expf(pv[n][r] - m_r[r]);
        psum[r] += e;
        Ps[wave][((lane >> 4) * 4 + r) * 72 + n * 16 + (lane & 15)] = f2bf(e);
      }
    }
    #pragma unroll
    for (int r = 0; r < 4; ++r) {
      psum[r] += __shfl_xor(psum[r], 1);
      psum[r] += __shfl_xor(psum[r], 2);
      psum[r] += __shfl_xor(psum[r], 4);
      psum[r] += __shfl_xor(psum[r], 8);
      l_r[r] = l_r[r] * corr[r] + psum[r];
    }
    #pragma unroll
    for (int n = 0; n < 4; ++n)
      #pragma unroll
      for (int r = 0; r < 4; ++r)
        acc_o[n][r] *= corr[r];

    // ---- O += P V ----
    short8 pa0 = *(const short8*)(&Ps[wave][(lane & 15) * 72 + (lane >> 4) * 8]);
    short8 pa1 = *(const short8*)(&Ps[wave][(lane & 15) * 72 + 32 + (lane >> 4) * 8]);
    #pragma unroll
    for (int n = 0; n < 4; ++n) {
      int rb = n * 16 + (lane & 15);
      int gq = lane >> 4;
      short8 vf0 = *(const short8*)(Vs + rb * 64 + ((gq ^ (rb & 7)) * 8));
      short8 vf1 = *(const short8*)(Vs + rb * 64 + (((gq + 4) ^ (rb & 7)) * 8));
      acc_o[n] = __builtin_amdgcn_mfma_f32_16x16x32_bf16(pa0, vf0, acc_o[n], 0, 0, 0);
      acc_o[n] = __builtin_amdgcn_mfma_f32_16x16x32_bf16(pa1, vf1, acc_o[n], 0, 0, 0);
    }
  }

  // ---- epilogue: O / l ----
  #pragma unroll
  for (int r = 0; r < 4; ++r) {
    float inv = 1.0f / l_r[r];
    int row = qt0 + wave * 16 + (lane >> 4) * 4 + r;
    unsigned short* op = out + (size_t)(b * SEQ + row) * DMODEL + h * HDIM + (lane & 15);
    #pragma unroll
    for (int n = 0; n < 4; ++n)
      op[n * 16] = f2bf(acc_o[n][r] * inv);
  }
}

// ---------------------------------------------------------------------------
// LayerNorm (+optional bf16 residual o); writes f32 out and optional bf16 outb
// ---------------------------------------------------------------------------
__global__ __launch_bounds__(256) void ln_kernel(
    const float* __restrict__ x, const unsigned short* __restrict__ o,
    float* __restrict__ out, unsigned short* __restrict__ outb,
    const float* __restrict__ g, const float* __restrict__ bta) {
  int n = blockIdx.x;
  int t = threadIdx.x;
  __shared__ float red[256];
  float vals[3];
  float sum = 0.f;
  #pragma unroll
  for (int i = 0; i < 3; ++i) {
    int d = t + i * 256;
    float val = x[(size_t)n * DMODEL + d];
    if (o) val += bf2f(o[(size_t)n * DMODEL + d]);
    vals[i] = val;
    sum += val;
  }
  red[t] = sum; __syncthreads();
  for (int off = 128; off; off >>= 1) {
    if (t < off) red[t] += red[t + off];
    __syncthreads();
  }
  float mu = red[0] * (1.0f / DMODEL);
  __syncthreads();
  float vs = 0.f;
  #pragma unroll
  for (int i = 0; i < 3; ++i) {
    float dlt = vals[i] - mu;
    vs += dlt * dlt;
  }
  red[t] = vs; __syncthreads();
  for (int off = 128; off; off >>= 1) {
    if (t < off) red[t] += red[t + off];
    __syncthreads();
  }
  float rstd = rsqrtf(red[0] * (1.0f / DMODEL) + 1e-5f);
  __syncthreads();
  #pragma unroll
  for (int i = 0; i < 3; ++i) {
    int d = t + i * 256;
    float val = (vals[i] - mu) * rstd * g[d] + bta[d];
    out[(size_t)n * DMODEL + d] = val;
    if (outb) outb[(size_t)n * DMODEL + d] = f2bf(val);
  }
}

// ---------------------------------------------------------------------------
__global__ __launch_bounds__(256) void pool_kernel(
    const float* __restrict__ xin, float* __restrict__ pooled) {
  int blk = blockIdx.x;
  int b = blk / (DMODEL / 256);
  int dc = blk % (DMODEL / 256);
  int d = dc * 256 + threadIdx.x;
  float s_ = 0.f;
  for (int s = 0; s < SEQ; ++s)
    s_ += xin[(size_t)(b * SEQ + s) * DMODEL + d];
  pooled[b * DMODEL + d] = s_ * (1.0f / SEQ);
}

__global__ __launch_bounds__(256) void classifier_kernel(
    const float* __restrict__ pooled, const float* __restrict__ Wfc,
    const float* __restrict__ bfc, float* __restrict__ out) {
  int b = blockIdx.x;
  int t = threadIdx.x;
  __shared__ float s0[256], s1[256];
  float acc0 = 0.f, acc1 = 0.f;
  for (int d = t; d < DMODEL; d += 256) {
    float p = pooled[b * DMODEL + d];
    acc0 += p * Wfc[d * NCLS + 0];
    acc1 += p * Wfc[d * NCLS + 1];
  }
  s0[t] = acc0; s1[t] = acc1; __syncthreads();
  for (int off = 128; off; off >>= 1) {
    if (t < off) { s0[t] += s0[t + off]; s1[t] += s1[t + off]; }
    __syncthreads();
  }
  if (t == 0) {
    float l0 = s0[0] + bfc[0], l1 = s1[0] + bfc[1];
    float m = fmaxf(l0, l1);
    float lse = m + logf(expf(l0 - m) + expf(l1 - m));
    out[b * NCLS + 0] = l0 - lse;
    out[b * NCLS + 1] = l1 - lse;
  }
}

// ---------------------------------------------------------------------------
extern "C" void kernel_launch(void* const* d_in, const int* in_sizes, int n_in,
                              void* d_out, int out_size, void* d_ws, size_t ws_size,
                              hipStream_t stream) {
  const int*   text  = (const int*)d_in[0];
  const int*   mask  = (const int*)d_in[1];
  const float* emb   = (const float*)d_in[2];
  const float* Wq    = (const float*)d_in[3];
  const float* bq    = (const float*)d_in[4];
  const float* Wk    = (const float*)d_in[5];
  const float* bk    = (const float*)d_in[6];
  const float* Wv    = (const float*)d_in[7];
  const float* bv    = (const float*)d_in[8];
  const float* Wo    = (const float*)d_in[9];
  const float* bo    = (const float*)d_in[10];
  const float* W1    = (const float*)d_in[11];
  const float* b1    = (const float*)d_in[12];
  const float* W2    = (const float*)d_in[13];
  const float* b2    = (const float*)d_in[14];
  const float* ln1_g = (const float*)d_in[15];
  const float* ln1_b = (const float*)d_in[16];
  const float* ln2_g = (const float*)d_in[17];
  const float* ln2_b = (const float*)d_in[18];
  const float* lnf_g = (const float*)d_in[19];
  const float* lnf_b = (const float*)d_in[20];
  const float* Wfc   = (const float*)d_in[21];
  const float* bfc   = (const float*)d_in[22];

  const size_t ND = (size_t)NTOK * DMODEL;
  const size_t NF = (size_t)NTOK * FFDIM;
  const size_t WDD = (size_t)DMODEL * DMODEL;
  const size_t WDF = (size_t)DMODEL * FFDIM;

  float* xf     = (float*)d_ws;                   // [N,D] f32 residual
  float* pooled = xf + ND;                        // [B,D]
  unsigned short* xb   = (unsigned short*)(pooled + BATCH * DMODEL);  // [N,D]
  unsigned short* qkvb = xb + ND;                 // [N,2304]; also o/ffn2 out
  unsigned short* vTb  = qkvb + (size_t)NTOK * QKVN;  // [B*H*64][SEQ]
  unsigned short* aob  = vTb + ND;                // [N,D] attention out
  unsigned short* h1b  = aob + ND;                // [N,FF]
  unsigned short* wqkvT = h1b + NF;               // [2304][768]
  unsigned short* woT  = wqkvT + 3 * WDD;
  unsigned short* w1T  = woT + WDD;               // [FF][D]
  unsigned short* w2T  = w1T + WDF;               // [D][FF]
  unsigned short* ob   = qkvb;                    // alias: o-proj / ffn2 output

  dim3 gD(DMODEL / BN, NTOK / BM);    // (6, 32)
  dim3 gQKV(QKVN / BN, NTOK / BM);    // (18, 32)
  dim3 gF(FFDIM / BN, NTOK / BM);     // (24, 32)

  embed_kernel<<<NTOK, 256, 0, stream>>>(text, emb, xf, xb);

  for (int l = 0; l < LAYERS; ++l) {
    const float* wq = Wq + (size_t)l * WDD;
    const float* wk = Wk + (size_t)l * WDD;
    const float* wv = Wv + (size_t)l * WDD;
    const float* wo = Wo + (size_t)l * WDD;
    const float* w1 = W1 + (size_t)l * WDF;
    const float* w2 = W2 + (size_t)l * WDF;

    wconv_kernel<<<dim3(12, 12), 256, 0, stream>>>(wq, wqkvT, DMODEL, DMODEL);
    wconv_kernel<<<dim3(12, 12), 256, 0, stream>>>(wk, wqkvT + WDD, DMODEL, DMODEL);
    wconv_kernel<<<dim3(12, 12), 256, 0, stream>>>(wv, wqkvT + 2 * WDD, DMODEL, DMODEL);
    wconv_kernel<<<dim3(12, 12), 256, 0, stream>>>(wo, woT, DMODEL, DMODEL);
    wconv_kernel<<<dim3(48, 12), 256, 0, stream>>>(w1, w1T, DMODEL, FFDIM);
    wconv_kernel<<<dim3(12, 48), 256, 0, stream>>>(w2, w2T, FFDIM, DMODEL);

    // fused QKV projection (V written transposed to vTb)
    gemm_mfma_kernel<<<gQKV, 256, 0, stream>>>(
        xb, wqkvT, bq + l * DMODEL, bk + l * DMODEL, bv + l * DMODEL,
        qkvb, vTb, NTOK, QKVN, DMODEL, 1, 0);

    attention_mfma_kernel<<<BATCH * NHEAD * (SEQ / 64), 256, 0, stream>>>(
        qkvb, vTb, mask, aob);

    gemm_mfma_kernel<<<gD, 256, 0, stream>>>(
        aob, woT, bo + l * DMODEL, nullptr, nullptr, ob, nullptr,
        NTOK, DMODEL, DMODEL, 1, 0);
    ln_kernel<<<NTOK, 256, 0, stream>>>(xf, ob, xf, xb, ln1_g + l * DMODEL, ln1_b + l * DMODEL);
    gemm_mfma_kernel<<<gF, 256, 0, stream>>>(
        xb, w1T, b1 + l * FFDIM, nullptr, nullptr, h1b, nullptr,
        NTOK, FFDIM, DMODEL, 1, 1);
    gemm_mfma_kernel<<<gD, 256, 0, stream>>>(
        h1b, w2T, b2 + l * DMODEL, nullptr, nullptr, ob, nullptr,
        NTOK, DMODEL, FFDIM, 1, 0);
    ln_kernel<<<NTOK, 256, 0, stream>>>(xf, ob, xf, xb, ln2_g + l * DMODEL, ln2_b + l * DMODEL);
  }

  // final LN in-place on xf, then pool + classify
  ln_kernel<<<NTOK, 256, 0, stream>>>(xf, nullptr, xf, nullptr, lnf_g, lnf_b);
  pool_kernel<<<BATCH * (DMODEL / 256), 256, 0, stream>>>(xf, pooled);
  classifier_kernel<<<BATCH, 256, 0, stream>>>(pooled, Wfc, bfc, (float*)d_out);
}

// Round 6
// 770.082 us; speedup vs baseline: 13.2467x; 1.1699x over previous
//
#include <hip/hip_runtime.h>
#include <hip/hip_bf16.h>
#include <math.h>

// Problem constants (match reference)
#define LAYERS 4
#define DMODEL 768
#define NHEAD 12
#define HDIM 64
#define FFDIM 3072
#define VOCAB 32000
#define NCLS 2
#define BATCH 8
#define SEQ 512
#define NTOK (BATCH * SEQ)   // 4096
#define QKVN (3 * DMODEL)    // 2304

typedef __attribute__((ext_vector_type(8))) short short8;      // 8 bf16 (4 VGPR)
typedef __attribute__((ext_vector_type(8))) unsigned short ushortx8;
typedef __attribute__((ext_vector_type(4))) float f32x4;

__device__ __forceinline__ float bf2f(unsigned short u) {
  return __uint_as_float(((unsigned)u) << 16);
}
__device__ __forceinline__ unsigned short f2bf(float x) {
  unsigned u = __float_as_uint(x);
  unsigned r = (u + 0x7fffu + ((u >> 16) & 1u)) >> 16;   // RNE
  return (unsigned short)r;
}

// async global->LDS, 16 bytes per lane (lds ptr = wave-uniform base + lane*16)
__device__ __forceinline__ void gload16(const void* gp, void* lp) {
  __builtin_amdgcn_global_load_lds(
      (const __attribute__((address_space(1))) void*)((unsigned long long)gp),
      (__attribute__((address_space(3))) void*)((unsigned int)(unsigned long long)lp),
      16, 0, 0);
}

// ---------------------------------------------------------------------------
// Embedding + positional encoding; writes f32 x (residual) and bf16 xb
// ---------------------------------------------------------------------------
__global__ __launch_bounds__(256) void embed_kernel(
    const int* __restrict__ text, const float* __restrict__ emb,
    float* __restrict__ x, unsigned short* __restrict__ xb) {
  int n = blockIdx.x;
  int t = threadIdx.x;
  int tok = text[n];
  int s = n % SEQ;
  const float sqrtD = 27.712812921102035f;
  const float nlog10k_over_d = -9.210340371976184f / 768.0f;
  #pragma unroll
  for (int i = 0; i < 3; ++i) {
    int d = t + i * 256;
    int j = d >> 1;
    float freq = expf((float)(2 * j) * nlog10k_over_d);
    float ang = (float)s * freq;
    float pe = (d & 1) ? cosf(ang) : sinf(ang);
    float val = emb[(size_t)tok * DMODEL + d] * sqrtD + pe;
    x[(size_t)n * DMODEL + d] = val;
    xb[(size_t)n * DMODEL + d] = f2bf(val);
  }
}

// ---------------------------------------------------------------------------
// Weight convert+transpose tile body: W[K][N] f32 -> Wt[N][K] bf16, 64x64 tile
// ---------------------------------------------------------------------------
__device__ __forceinline__ void wconv_tile(
    const float* __restrict__ W, unsigned short* __restrict__ Wt,
    int K, int N, int k0, int n0, int tid, float (*t)[65]) {
  {
    int r = tid >> 2, c4 = (tid & 3) * 16;
    #pragma unroll
    for (int j = 0; j < 4; ++j) {
      float4 vv = *(const float4*)(W + (size_t)(k0 + r) * N + n0 + c4 + j * 4);
      t[r][c4 + j * 4 + 0] = vv.x; t[r][c4 + j * 4 + 1] = vv.y;
      t[r][c4 + j * 4 + 2] = vv.z; t[r][c4 + j * 4 + 3] = vv.w;
    }
  }
  __syncthreads();
  {
    int n = tid >> 2, k4 = (tid & 3) * 16;
    ushortx8 u0, u1;
    #pragma unroll
    for (int j = 0; j < 8; ++j) u0[j] = f2bf(t[k4 + j][n]);
    #pragma unroll
    for (int j = 0; j < 8; ++j) u1[j] = f2bf(t[k4 + 8 + j][n]);
    *(ushortx8*)(Wt + (size_t)(n0 + n) * K + k0 + k4) = u0;
    *(ushortx8*)(Wt + (size_t)(n0 + n) * K + k0 + k4 + 8) = u1;
  }
}

// One dispatch converts a whole layer's 6 weight matrices. 1728 blocks:
// [0,576): wq/wk/wv/wo (144 tiles each), [576,1152): w1, [1152,1728): w2.
__global__ __launch_bounds__(256) void wconv_layer_kernel(
    const float* __restrict__ wq, const float* __restrict__ wk,
    const float* __restrict__ wv, const float* __restrict__ wo,
    const float* __restrict__ w1, const float* __restrict__ w2,
    unsigned short* __restrict__ wqkvT, unsigned short* __restrict__ woT,
    unsigned short* __restrict__ w1T, unsigned short* __restrict__ w2T) {
  __shared__ float t[64][65];
  const size_t WDD = (size_t)DMODEL * DMODEL;
  int blk = blockIdx.x;
  const float* W; unsigned short* Wt; int K, N, tx, ty;
  if (blk < 576) {
    int region = blk / 144, r = blk % 144;
    tx = r % 12; ty = r / 12; K = DMODEL; N = DMODEL;
    W = (region == 0) ? wq : (region == 1) ? wk : (region == 2) ? wv : wo;
    Wt = (region < 3) ? (wqkvT + (size_t)region * WDD) : woT;
  } else if (blk < 1152) {
    int r = blk - 576; tx = r % 48; ty = r / 48; K = DMODEL; N = FFDIM;
    W = w1; Wt = w1T;
  } else {
    int r = blk - 1152; tx = r % 12; ty = r / 12; K = FFDIM; N = DMODEL;
    W = w2; Wt = w2T;
  }
  wconv_tile(W, Wt, K, N, ty * 64, tx * 64, threadIdx.x, t);
}

// ---------------------------------------------------------------------------
// bf16 MFMA GEMM: C[M][N] = A[M][K] @ Bt[N][K]^T + bias
// BM=128 x TBN tile, BK=64, 4 waves. TBN=128: 4x4 frags; TBN=64: 4x2 frags.
// XCD-aware bijective block swizzle (grid must be a multiple of 8).
//
// LDS swizzle invariant (both sides): staging stores global k-group g of row
// r at slot g ^ (r&7); fragment rows have r&7 == lane&7, and lane needs
// global group (lane>>4) + kh*4, so the read slot is
//   gs = (lane>>4) ^ (lane&7) ^ (kh*4)      [VERIFIED round 4; round 5's
// "simplified" form cancelled the row-XOR and broke correctness.]
// ---------------------------------------------------------------------------
#define BM 128
#define BK 64
template <int TBN>
__global__ __launch_bounds__(256, 2) void gemm_mfma_kernel(
    const unsigned short* __restrict__ A,    // [M][K] bf16
    const unsigned short* __restrict__ Bt,   // [N][K] bf16
    const float* __restrict__ bias,          // [N] (or Q region)
    const float* __restrict__ biasK,         // K region (QKV mode)
    const float* __restrict__ biasV,         // V region (QKV mode)
    void* __restrict__ Cout,                 // [M][N] f32 or bf16
    unsigned short* __restrict__ vTout,      // QKV mode V^T output
    int M, int N, int K, int out_bf16, int relu) {
  constexpr int NF = TBN / 32;               // n-fragments per wave
  __shared__ unsigned short As[BM * BK];
  __shared__ unsigned short Bs[TBN * BK];

  const int tid = threadIdx.x;
  const int lane = tid & 63;
  const int wave = tid >> 6;

  // XCD swizzle: hardware block orig -> logical tile swz (x-first chunks)
  unsigned nwg = gridDim.x * gridDim.y;
  unsigned orig = blockIdx.y * gridDim.x + blockIdx.x;
  unsigned swz = (orig & 7) * (nwg >> 3) + (orig >> 3);
  const int m0 = (swz / gridDim.x) * BM;
  const int n0 = (swz % gridDim.x) * TBN;

  const int wrow = (wave >> 1) * 64;
  const int wcol = (wave & 1) * (TBN / 2);

  const int lrow = lane >> 3;
  const int kgrp = (lane & 7) ^ lrow;

  const unsigned short* Ab = A  + (size_t)(m0 + 32 * wave + lrow) * K + kgrp * 8;
  const unsigned short* Bb = Bt + (size_t)(n0 + (TBN / 4) * wave + lrow) * K + kgrp * 8;
  unsigned short* AsW = As + wave * 2048 + lane * 8;
  unsigned short* BsW = Bs + wave * (TBN / 4) * BK + lane * 8;

  f32x4 acc[4][NF];
  #pragma unroll
  for (int m = 0; m < 4; ++m)
    #pragma unroll
    for (int n = 0; n < NF; ++n)
      acc[m][n] = (f32x4){0.f, 0.f, 0.f, 0.f};

  const int g0 = (lane >> 4) ^ (lane & 7);

  for (int k0 = 0; k0 < K; k0 += BK) {
    __syncthreads();
    #pragma unroll
    for (int i = 0; i < 4; ++i)
      gload16(Ab + (size_t)(8 * i) * K + k0, AsW + i * 512);
    #pragma unroll
    for (int i = 0; i < TBN / 32; ++i)
      gload16(Bb + (size_t)(8 * i) * K + k0, BsW + i * 512);
    __syncthreads();
    #pragma unroll
    for (int kh = 0; kh < 2; ++kh) {
      const int gs = g0 ^ (kh * 4);
      short8 a[4], b[NF];
      #pragma unroll
      for (int m = 0; m < 4; ++m) {
        int r = wrow + m * 16 + (lane & 15);
        a[m] = *(const short8*)(As + r * 64 + gs * 8);
      }
      #pragma unroll
      for (int n = 0; n < NF; ++n) {
        int r = wcol + n * 16 + (lane & 15);
        b[n] = *(const short8*)(Bs + r * 64 + gs * 8);
      }
      #pragma unroll
      for (int m = 0; m < 4; ++m)
        #pragma unroll
        for (int n = 0; n < NF; ++n)
          acc[m][n] = __builtin_amdgcn_mfma_f32_16x16x32_bf16(a[m], b[n], acc[m][n], 0, 0, 0);
    }
  }

  const int crow0 = m0 + wrow + (lane >> 4) * 4;
  const int ccol0 = n0 + wcol + (lane & 15);
  #pragma unroll
  for (int n = 0; n < NF; ++n) {
    int c = ccol0 + n * 16;
    float bv;
    if (vTout) bv = (c < DMODEL) ? bias[c]
                  : (c < 2 * DMODEL) ? biasK[c - DMODEL] : biasV[c - 2 * DMODEL];
    else bv = bias[c];
    bool tovT = (vTout != nullptr) && (c >= 2 * DMODEL);
    int hd = c - 2 * DMODEL;   // h*64+d when tovT
    #pragma unroll
    for (int m = 0; m < 4; ++m) {
      #pragma unroll
      for (int r = 0; r < 4; ++r) {
        float val = acc[m][n][r] + bv;
        if (relu) val = fmaxf(val, 0.f);
        int mr = crow0 + m * 16 + r;
        if (tovT) {
          vTout[((size_t)((mr >> 9) * NHEAD + (hd >> 6)) * HDIM + (hd & 63)) * SEQ + (mr & 511)] = f2bf(val);
        } else if (out_bf16) {
          ((unsigned short*)Cout)[(size_t)mr * N + c] = f2bf(val);
        } else {
          ((float*)Cout)[(size_t)mr * N + c] = val;
        }
      }
    }
  }
}

// ---------------------------------------------------------------------------
// MFMA flash attention: one block per (b, h, 64-query tile); 4 waves.
// Q in registers; K/V staged swizzled via global_load_lds; wave-parallel
// online softmax on MFMA C-layout; P -> bf16 LDS -> PV MFMA.
// XCD swizzle keeps a (b,h)'s 8 q-tiles on one XCD (shared K/V in L2).
// ---------------------------------------------------------------------------
__global__ __launch_bounds__(256) void attention_mfma_kernel(
    const unsigned short* __restrict__ qkv,  // [NTOK][2304] bf16 (Q|K|V)
    const unsigned short* __restrict__ vT,   // [(b*H+h)*64+d][SEQ] bf16
    const int* __restrict__ mask,            // [B][SEQ]
    unsigned short* __restrict__ out) {      // [NTOK][768] bf16
  unsigned orig = blockIdx.x;
  unsigned blk = (orig & 7) * (gridDim.x >> 3) + (orig >> 3);
  int qt0 = (blk % (SEQ / 64)) * 64;
  int h = (blk / (SEQ / 64)) % NHEAD;
  int b = blk / ((SEQ / 64) * NHEAD);
  int tid = threadIdx.x, lane = tid & 63, wave = tid >> 6;

  __shared__ unsigned short Ks[64 * 64];     // swizzled [key][dimgrp ^ (key&7)]
  __shared__ unsigned short Vs[64 * 64];     // swizzled [d][keygrp ^ (d&7)]
  __shared__ unsigned short Ps[4][16 * 72];  // per-wave P, stride 72 bf16
  __shared__ int msk_s[SEQ];

  if (tid < SEQ / 4) *(int4*)&msk_s[tid * 4] = *(const int4*)&mask[b * SEQ + tid * 4];

  int qrow = qt0 + wave * 16 + (lane & 15);
  const unsigned short* qp = qkv + (size_t)(b * SEQ + qrow) * QKVN + h * HDIM + (lane >> 4) * 8;
  short8 qf0 = *(const short8*)qp;
  short8 qf1 = *(const short8*)(qp + 32);

  float m_r[4], l_r[4];
  f32x4 acc_o[4];
  #pragma unroll
  for (int r = 0; r < 4; ++r) { m_r[r] = -3.0e38f; l_r[r] = 0.f; }
  #pragma unroll
  for (int n = 0; n < 4; ++n) acc_o[n] = (f32x4){0.f, 0.f, 0.f, 0.f};

  for (int kt = 0; kt < SEQ / 64; ++kt) {
    __syncthreads();
    #pragma unroll
    for (int it = 0; it < 2; ++it) {
      int ck = it * 256 + tid;
      int row = ck >> 3, g = ck & 7;
      gload16(qkv + (size_t)(b * SEQ + kt * 64 + row) * QKVN + DMODEL + h * HDIM + ((g ^ (row & 7)) * 8),
              Ks + ck * 8);
      gload16(vT + (size_t)((b * NHEAD + h) * HDIM + row) * SEQ + kt * 64 + ((g ^ (row & 7)) * 8),
              Vs + ck * 8);
    }
    __syncthreads();

    // ---- S = Q K^T ----
    f32x4 acc_s[4];
    #pragma unroll
    for (int n = 0; n < 4; ++n) acc_s[n] = (f32x4){0.f, 0.f, 0.f, 0.f};
    #pragma unroll
    for (int n = 0; n < 4; ++n) {
      int rb = n * 16 + (lane & 15);
      int gq = lane >> 4;
      short8 kf0 = *(const short8*)(Ks + rb * 64 + ((gq ^ (rb & 7)) * 8));
      short8 kf1 = *(const short8*)(Ks + rb * 64 + (((gq + 4) ^ (rb & 7)) * 8));
      acc_s[n] = __builtin_amdgcn_mfma_f32_16x16x32_bf16(qf0, kf0, acc_s[n], 0, 0, 0);
      acc_s[n] = __builtin_amdgcn_mfma_f32_16x16x32_bf16(qf1, kf1, acc_s[n], 0, 0, 0);
    }

    // ---- online softmax ----
    float pv[4][4], rmax[4];
    #pragma unroll
    for (int r = 0; r < 4; ++r) rmax[r] = -3.0e38f;
    #pragma unroll
    for (int n = 0; n < 4; ++n) {
      int msk = msk_s[kt * 64 + n * 16 + (lane & 15)];
      #pragma unroll
      for (int r = 0; r < 4; ++r) {
        float s = acc_s[n][r] * 0.125f;
        if (msk == 0) s = -1e9f;
        pv[n][r] = s;
        rmax[r] = fmaxf(rmax[r], s);
      }
    }
    #pragma unroll
    for (int r = 0; r < 4; ++r) {
      rmax[r] = fmaxf(rmax[r], __shfl_xor(rmax[r], 1));
      rmax[r] = fmaxf(rmax[r], __shfl_xor(rmax[r], 2));
      rmax[r] = fmaxf(rmax[r], __shfl_xor(rmax[r], 4));
      rmax[r] = fmaxf(rmax[r], __shfl_xor(rmax[r], 8));
    }
    float corr[4], psum[4];
    #pragma unroll
    for (int r = 0; r < 4; ++r) {
      float mn = fmaxf(m_r[r], rmax[r]);
      corr[r] = expf(m_r[r] - mn);
      m_r[r] = mn;
      psum[r] = 0.f;
    }
    #pragma unroll
    for (int n = 0; n < 4; ++n) {
      #pragma unroll
      for (int r = 0; r < 4; ++r) {
        float e = expf(pv[n][r] - m_r[r]);
        psum[r] += e;
        Ps[wave][((lane >> 4) * 4 + r) * 72 + n * 16 + (lane & 15)] = f2bf(e);
      }
    }
    #pragma unroll
    for (int r = 0; r < 4; ++r) {
      psum[r] += __shfl_xor(psum[r], 1);
      psum[r] += __shfl_xor(psum[r], 2);
      psum[r] += __shfl_xor(psum[r], 4);
      psum[r] += __shfl_xor(psum[r], 8);
      l_r[r] = l_r[r] * corr[r] + psum[r];
    }
    #pragma unroll
    for (int n = 0; n < 4; ++n)
      #pragma unroll
      for (int r = 0; r < 4; ++r)
        acc_o[n][r] *= corr[r];

    // ---- O += P V ----
    short8 pa0 = *(const short8*)(&Ps[wave][(lane & 15) * 72 + (lane >> 4) * 8]);
    short8 pa1 = *(const short8*)(&Ps[wave][(lane & 15) * 72 + 32 + (lane >> 4) * 8]);
    #pragma unroll
    for (int n = 0; n < 4; ++n) {
      int rb = n * 16 + (lane & 15);
      int gq = lane >> 4;
      short8 vf0 = *(const short8*)(Vs + rb * 64 + ((gq ^ (rb & 7)) * 8));
      short8 vf1 = *(const short8*)(Vs + rb * 64 + (((gq + 4) ^ (rb & 7)) * 8));
      acc_o[n] = __builtin_amdgcn_mfma_f32_16x16x32_bf16(pa0, vf0, acc_o[n], 0, 0, 0);
      acc_o[n] = __builtin_amdgcn_mfma_f32_16x16x32_bf16(pa1, vf1, acc_o[n], 0, 0, 0);
    }
  }

  #pragma unroll
  for (int r = 0; r < 4; ++r) {
    float inv = 1.0f / l_r[r];
    int row = qt0 + wave * 16 + (lane >> 4) * 4 + r;
    unsigned short* op = out + (size_t)(b * SEQ + row) * DMODEL + h * HDIM + (lane & 15);
    #pragma unroll
    for (int n = 0; n < 4; ++n)
      op[n * 16] = f2bf(acc_o[n][r] * inv);
  }
}

// ---------------------------------------------------------------------------
// LayerNorm (+optional bf16 residual o); writes f32 out and optional bf16 outb
// ---------------------------------------------------------------------------
__global__ __launch_bounds__(256) void ln_kernel(
    const float* __restrict__ x, const unsigned short* __restrict__ o,
    float* __restrict__ out, unsigned short* __restrict__ outb,
    const float* __restrict__ g, const float* __restrict__ bta) {
  int n = blockIdx.x;
  int t = threadIdx.x;
  __shared__ float red[256];
  float vals[3];
  float sum = 0.f;
  #pragma unroll
  for (int i = 0; i < 3; ++i) {
    int d = t + i * 256;
    float val = x[(size_t)n * DMODEL + d];
    if (o) val += bf2f(o[(size_t)n * DMODEL + d]);
    vals[i] = val;
    sum += val;
  }
  red[t] = sum; __syncthreads();
  for (int off = 128; off; off >>= 1) {
    if (t < off) red[t] += red[t + off];
    __syncthreads();
  }
  float mu = red[0] * (1.0f / DMODEL);
  __syncthreads();
  float vs = 0.f;
  #pragma unroll
  for (int i = 0; i < 3; ++i) {
    float dlt = vals[i] - mu;
    vs += dlt * dlt;
  }
  red[t] = vs; __syncthreads();
  for (int off = 128; off; off >>= 1) {
    if (t < off) red[t] += red[t + off];
    __syncthreads();
  }
  float rstd = rsqrtf(red[0] * (1.0f / DMODEL) + 1e-5f);
  __syncthreads();
  #pragma unroll
  for (int i = 0; i < 3; ++i) {
    int d = t + i * 256;
    float val = (vals[i] - mu) * rstd * g[d] + bta[d];
    out[(size_t)n * DMODEL + d] = val;
    if (outb) outb[(size_t)n * DMODEL + d] = f2bf(val);
  }
}

// ---------------------------------------------------------------------------
__global__ __launch_bounds__(256) void pool_kernel(
    const float* __restrict__ xin, float* __restrict__ pooled) {
  int blk = blockIdx.x;
  int b = blk / (DMODEL / 256);
  int dc = blk % (DMODEL / 256);
  int d = dc * 256 + threadIdx.x;
  float s_ = 0.f;
  for (int s = 0; s < SEQ; ++s)
    s_ += xin[(size_t)(b * SEQ + s) * DMODEL + d];
  pooled[b * DMODEL + d] = s_ * (1.0f / SEQ);
}

__global__ __launch_bounds__(256) void classifier_kernel(
    const float* __restrict__ pooled, const float* __restrict__ Wfc,
    const float* __restrict__ bfc, float* __restrict__ out) {
  int b = blockIdx.x;
  int t = threadIdx.x;
  __shared__ float s0[256], s1[256];
  float acc0 = 0.f, acc1 = 0.f;
  for (int d = t; d < DMODEL; d += 256) {
    float p = pooled[b * DMODEL + d];
    acc0 += p * Wfc[d * NCLS + 0];
    acc1 += p * Wfc[d * NCLS + 1];
  }
  s0[t] = acc0; s1[t] = acc1; __syncthreads();
  for (int off = 128; off; off >>= 1) {
    if (t < off) { s0[t] += s0[t + off]; s1[t] += s1[t + off]; }
    __syncthreads();
  }
  if (t == 0) {
    float l0 = s0[0] + bfc[0], l1 = s1[0] + bfc[1];
    float m = fmaxf(l0, l1);
    float lse = m + logf(expf(l0 - m) + expf(l1 - m));
    out[b * NCLS + 0] = l0 - lse;
    out[b * NCLS + 1] = l1 - lse;
  }
}

// ---------------------------------------------------------------------------
extern "C" void kernel_launch(void* const* d_in, const int* in_sizes, int n_in,
                              void* d_out, int out_size, void* d_ws, size_t ws_size,
                              hipStream_t stream) {
  const int*   text  = (const int*)d_in[0];
  const int*   mask  = (const int*)d_in[1];
  const float* emb   = (const float*)d_in[2];
  const float* Wq    = (const float*)d_in[3];
  const float* bq    = (const float*)d_in[4];
  const float* Wk    = (const float*)d_in[5];
  const float* bk    = (const float*)d_in[6];
  const float* Wv    = (const float*)d_in[7];
  const float* bv    = (const float*)d_in[8];
  const float* Wo    = (const float*)d_in[9];
  const float* bo    = (const float*)d_in[10];
  const float* W1    = (const float*)d_in[11];
  const float* b1    = (const float*)d_in[12];
  const float* W2    = (const float*)d_in[13];
  const float* b2    = (const float*)d_in[14];
  const float* ln1_g = (const float*)d_in[15];
  const float* ln1_b = (const float*)d_in[16];
  const float* ln2_g = (const float*)d_in[17];
  const float* ln2_b = (const float*)d_in[18];
  const float* lnf_g = (const float*)d_in[19];
  const float* lnf_b = (const float*)d_in[20];
  const float* Wfc   = (const float*)d_in[21];
  const float* bfc   = (const float*)d_in[22];

  const size_t ND = (size_t)NTOK * DMODEL;
  const size_t NF = (size_t)NTOK * FFDIM;
  const size_t WDD = (size_t)DMODEL * DMODEL;
  const size_t WDF = (size_t)DMODEL * FFDIM;

  float* xf     = (float*)d_ws;                   // [N,D] f32 residual
  float* pooled = xf + ND;                        // [B,D]
  unsigned short* xb   = (unsigned short*)(pooled + BATCH * DMODEL);  // [N,D]
  unsigned short* qkvb = xb + ND;                 // [N,2304]; also o/ffn2 out
  unsigned short* vTb  = qkvb + (size_t)NTOK * QKVN;  // [B*H*64][SEQ]
  unsigned short* aob  = vTb + ND;                // [N,D] attention out
  unsigned short* h1b  = aob + ND;                // [N,FF]
  unsigned short* wqkvT = h1b + NF;               // [2304][768]
  unsigned short* woT  = wqkvT + 3 * WDD;
  unsigned short* w1T  = woT + WDD;               // [FF][D]
  unsigned short* w2T  = w1T + WDF;               // [D][FF]
  unsigned short* ob   = qkvb;                    // alias: o-proj / ffn2 output

  dim3 gD64(DMODEL / 64, NTOK / BM);   // (12, 32) = 384 blocks, TBN=64
  dim3 gQKV(QKVN / 128, NTOK / BM);    // (18, 32) = 576 blocks, TBN=128
  dim3 gF(FFDIM / 128, NTOK / BM);     // (24, 32) = 768 blocks, TBN=128

  embed_kernel<<<NTOK, 256, 0, stream>>>(text, emb, xf, xb);

  for (int l = 0; l < LAYERS; ++l) {
    wconv_layer_kernel<<<1728, 256, 0, stream>>>(
        Wq + (size_t)l * WDD, Wk + (size_t)l * WDD, Wv + (size_t)l * WDD,
        Wo + (size_t)l * WDD, W1 + (size_t)l * WDF, W2 + (size_t)l * WDF,
        wqkvT, woT, w1T, w2T);

    // fused QKV projection (V written transposed to vTb)
    gemm_mfma_kernel<128><<<gQKV, 256, 0, stream>>>(
        xb, wqkvT, bq + l * DMODEL, bk + l * DMODEL, bv + l * DMODEL,
        qkvb, vTb, NTOK, QKVN, DMODEL, 1, 0);

    attention_mfma_kernel<<<BATCH * NHEAD * (SEQ / 64), 256, 0, stream>>>(
        qkvb, vTb, mask, aob);

    gemm_mfma_kernel<64><<<gD64, 256, 0, stream>>>(
        aob, woT, bo + l * DMODEL, nullptr, nullptr, ob, nullptr,
        NTOK, DMODEL, DMODEL, 1, 0);
    ln_kernel<<<NTOK, 256, 0, stream>>>(xf, ob, xf, xb, ln1_g + l * DMODEL, ln1_b + l * DMODEL);
    gemm_mfma_kernel<128><<<gF, 256, 0, stream>>>(
        xb, w1T, b1 + l * FFDIM, nullptr, nullptr, h1b, nullptr,
        NTOK, FFDIM, DMODEL, 1, 1);
    gemm_mfma_kernel<64><<<gD64, 256, 0, stream>>>(
        h1b, w2T, b2 + l * DMODEL, nullptr, nullptr, ob, nullptr,
        NTOK, DMODEL, FFDIM, 1, 0);
    ln_kernel<<<NTOK, 256, 0, stream>>>(xf, ob, xf, xb, ln2_g + l * DMODEL, ln2_b + l * DMODEL);
  }

  // final LN in-place on xf, then pool + classify
  ln_kernel<<<NTOK, 256, 0, stream>>>(xf, nullptr, xf, nullptr, lnf_g, lnf_b);
  pool_kernel<<<BATCH * (DMODEL / 256), 256, 0, stream>>>(xf, pooled);
  classifier_kernel<<<BATCH, 256, 0, stream>>>(pooled, Wfc, bfc, (float*)d_out);
}

// Round 7
// 688.671 us; speedup vs baseline: 14.8126x; 1.1182x over previous
//
#include <hip/hip_runtime.h>
#include <hip/hip_bf16.h>
#include <math.h>

// Problem constants (match reference)
#define LAYERS 4
#define DMODEL 768
#define NHEAD 12
#define HDIM 64
#define FFDIM 3072
#define VOCAB 32000
#define NCLS 2
#define BATCH 8
#define SEQ 512
#define NTOK (BATCH * SEQ)   // 4096
#define QKVN (3 * DMODEL)    // 2304

typedef __attribute__((ext_vector_type(8))) short short8;      // 8 bf16 (4 VGPR)
typedef __attribute__((ext_vector_type(8))) unsigned short ushortx8;
typedef __attribute__((ext_vector_type(4))) unsigned short ushortx4;
typedef __attribute__((ext_vector_type(4))) float f32x4;

__device__ __forceinline__ float bf2f(unsigned short u) {
  return __uint_as_float(((unsigned)u) << 16);
}
__device__ __forceinline__ unsigned short f2bf(float x) {
  unsigned u = __float_as_uint(x);
  unsigned r = (u + 0x7fffu + ((u >> 16) & 1u)) >> 16;   // RNE
  return (unsigned short)r;
}

// async global->LDS, 16 bytes per lane (lds ptr = wave-uniform base + lane*16)
__device__ __forceinline__ void gload16(const void* gp, void* lp) {
  __builtin_amdgcn_global_load_lds(
      (const __attribute__((address_space(1))) void*)((unsigned long long)gp),
      (__attribute__((address_space(3))) void*)((unsigned int)(unsigned long long)lp),
      16, 0, 0);
}

// ---------------------------------------------------------------------------
// Embedding + positional encoding; writes f32 x (residual) and bf16 xb
// ---------------------------------------------------------------------------
__global__ __launch_bounds__(256) void embed_kernel(
    const int* __restrict__ text, const float* __restrict__ emb,
    float* __restrict__ x, unsigned short* __restrict__ xb) {
  int n = blockIdx.x;
  int t = threadIdx.x;
  int tok = text[n];
  int s = n % SEQ;
  const float sqrtD = 27.712812921102035f;
  const float nlog10k_over_d = -9.210340371976184f / 768.0f;
  #pragma unroll
  for (int i = 0; i < 3; ++i) {
    int d = t + i * 256;
    int j = d >> 1;
    float freq = expf((float)(2 * j) * nlog10k_over_d);
    float ang = (float)s * freq;
    float pe = (d & 1) ? cosf(ang) : sinf(ang);
    float val = emb[(size_t)tok * DMODEL + d] * sqrtD + pe;
    x[(size_t)n * DMODEL + d] = val;
    xb[(size_t)n * DMODEL + d] = f2bf(val);
  }
}

// ---------------------------------------------------------------------------
// Weight convert+transpose tile body: W[K][N] f32 -> Wt[N][K] bf16, 64x64 tile
// ---------------------------------------------------------------------------
__device__ __forceinline__ void wconv_tile(
    const float* __restrict__ W, unsigned short* __restrict__ Wt,
    int K, int N, int k0, int n0, int tid, float (*t)[65]) {
  {
    int r = tid >> 2, c4 = (tid & 3) * 16;
    #pragma unroll
    for (int j = 0; j < 4; ++j) {
      float4 vv = *(const float4*)(W + (size_t)(k0 + r) * N + n0 + c4 + j * 4);
      t[r][c4 + j * 4 + 0] = vv.x; t[r][c4 + j * 4 + 1] = vv.y;
      t[r][c4 + j * 4 + 2] = vv.z; t[r][c4 + j * 4 + 3] = vv.w;
    }
  }
  __syncthreads();
  {
    int n = tid >> 2, k4 = (tid & 3) * 16;
    ushortx8 u0, u1;
    #pragma unroll
    for (int j = 0; j < 8; ++j) u0[j] = f2bf(t[k4 + j][n]);
    #pragma unroll
    for (int j = 0; j < 8; ++j) u1[j] = f2bf(t[k4 + 8 + j][n]);
    *(ushortx8*)(Wt + (size_t)(n0 + n) * K + k0 + k4) = u0;
    *(ushortx8*)(Wt + (size_t)(n0 + n) * K + k0 + k4 + 8) = u1;
  }
}

// All 4 layers' 6 weight matrices in ONE dispatch. 4 x 1728 = 6912 blocks.
// Per layer: [0,576): wq/wk/wv/wo (144 tiles each), [576,1152): w1, [1152,1728): w2
__global__ __launch_bounds__(256) void wconv_all_kernel(
    const float* __restrict__ Wq, const float* __restrict__ Wk,
    const float* __restrict__ Wv, const float* __restrict__ Wo,
    const float* __restrict__ W1, const float* __restrict__ W2,
    unsigned short* __restrict__ wqkvT, unsigned short* __restrict__ woT,
    unsigned short* __restrict__ w1T, unsigned short* __restrict__ w2T) {
  __shared__ float t[64][65];
  const size_t WDD = (size_t)DMODEL * DMODEL;
  const size_t WDF = (size_t)DMODEL * FFDIM;
  int l = blockIdx.x / 1728;
  int blk = blockIdx.x % 1728;
  const float* W; unsigned short* Wt; int K, N, tx, ty;
  if (blk < 576) {
    int region = blk / 144, r = blk % 144;
    tx = r % 12; ty = r / 12; K = DMODEL; N = DMODEL;
    W = (region == 0) ? (Wq + l * WDD) : (region == 1) ? (Wk + l * WDD)
      : (region == 2) ? (Wv + l * WDD) : (Wo + l * WDD);
    Wt = (region < 3) ? (wqkvT + (size_t)l * 3 * WDD + (size_t)region * WDD)
                      : (woT + (size_t)l * WDD);
  } else if (blk < 1152) {
    int r = blk - 576; tx = r % 48; ty = r / 48; K = DMODEL; N = FFDIM;
    W = W1 + l * WDF; Wt = w1T + (size_t)l * WDF;
  } else {
    int r = blk - 1152; tx = r % 12; ty = r / 12; K = FFDIM; N = DMODEL;
    W = W2 + l * WDF; Wt = w2T + (size_t)l * WDF;
  }
  wconv_tile(W, Wt, K, N, ty * 64, tx * 64, threadIdx.x, t);
}

// ---------------------------------------------------------------------------
// bf16 MFMA GEMM: C[M][N] = A[M][K] @ Bt[N][K]^T + bias
// BM=128 x TBN tile, BK=64, 4 waves. TBN=128: 4x4 frags; TBN=64: 4x2 frags.
// XCD-aware bijective block swizzle (grid must be a multiple of 8).
//
// LDS swizzle invariant (both sides): staging stores global k-group g of row
// r at slot g ^ (r&7); fragment rows have r&7 == lane&7, and lane needs
// global group (lane>>4) + kh*4, so the read slot is
//   gs = (lane>>4) ^ (lane&7) ^ (kh*4)      [VERIFIED round 4/6; do NOT
// algebraically "simplify" -- round 5 broke correctness that way.]
// ---------------------------------------------------------------------------
#define BM 128
#define BK 64
template <int TBN>
__global__ __launch_bounds__(256, 2) void gemm_mfma_kernel(
    const unsigned short* __restrict__ A,    // [M][K] bf16
    const unsigned short* __restrict__ Bt,   // [N][K] bf16
    const float* __restrict__ bias,          // [N] (or Q region)
    const float* __restrict__ biasK,         // K region (QKV mode)
    const float* __restrict__ biasV,         // V region (QKV mode)
    void* __restrict__ Cout,                 // [M][N] f32 or bf16
    unsigned short* __restrict__ vTout,      // QKV mode V^T output
    int M, int N, int K, int out_bf16, int relu) {
  constexpr int NF = TBN / 32;               // n-fragments per wave
  __shared__ unsigned short As[BM * BK];
  __shared__ unsigned short Bs[TBN * BK];

  const int tid = threadIdx.x;
  const int lane = tid & 63;
  const int wave = tid >> 6;

  // XCD swizzle: hardware block orig -> logical tile swz (x-first chunks)
  unsigned nwg = gridDim.x * gridDim.y;
  unsigned orig = blockIdx.y * gridDim.x + blockIdx.x;
  unsigned swz = (orig & 7) * (nwg >> 3) + (orig >> 3);
  const int m0 = (swz / gridDim.x) * BM;
  const int n0 = (swz % gridDim.x) * TBN;

  const int wrow = (wave >> 1) * 64;
  const int wcol = (wave & 1) * (TBN / 2);

  const int lrow = lane >> 3;
  const int kgrp = (lane & 7) ^ lrow;

  const unsigned short* Ab = A  + (size_t)(m0 + 32 * wave + lrow) * K + kgrp * 8;
  const unsigned short* Bb = Bt + (size_t)(n0 + (TBN / 4) * wave + lrow) * K + kgrp * 8;
  unsigned short* AsW = As + wave * 2048 + lane * 8;
  unsigned short* BsW = Bs + wave * (TBN / 4) * BK + lane * 8;

  f32x4 acc[4][NF];
  #pragma unroll
  for (int m = 0; m < 4; ++m)
    #pragma unroll
    for (int n = 0; n < NF; ++n)
      acc[m][n] = (f32x4){0.f, 0.f, 0.f, 0.f};

  const int g0 = (lane >> 4) ^ (lane & 7);

  for (int k0 = 0; k0 < K; k0 += BK) {
    __syncthreads();
    #pragma unroll
    for (int i = 0; i < 4; ++i)
      gload16(Ab + (size_t)(8 * i) * K + k0, AsW + i * 512);
    #pragma unroll
    for (int i = 0; i < TBN / 32; ++i)
      gload16(Bb + (size_t)(8 * i) * K + k0, BsW + i * 512);
    __syncthreads();
    #pragma unroll
    for (int kh = 0; kh < 2; ++kh) {
      const int gs = g0 ^ (kh * 4);
      short8 a[4], b[NF];
      #pragma unroll
      for (int m = 0; m < 4; ++m) {
        int r = wrow + m * 16 + (lane & 15);
        a[m] = *(const short8*)(As + r * 64 + gs * 8);
      }
      #pragma unroll
      for (int n = 0; n < NF; ++n) {
        int r = wcol + n * 16 + (lane & 15);
        b[n] = *(const short8*)(Bs + r * 64 + gs * 8);
      }
      #pragma unroll
      for (int m = 0; m < 4; ++m)
        #pragma unroll
        for (int n = 0; n < NF; ++n)
          acc[m][n] = __builtin_amdgcn_mfma_f32_16x16x32_bf16(a[m], b[n], acc[m][n], 0, 0, 0);
    }
  }

  const int crow0 = m0 + wrow + (lane >> 4) * 4;
  const int ccol0 = n0 + wcol + (lane & 15);
  #pragma unroll
  for (int n = 0; n < NF; ++n) {
    int c = ccol0 + n * 16;
    float bv;
    if (vTout) bv = (c < DMODEL) ? bias[c]
                  : (c < 2 * DMODEL) ? biasK[c - DMODEL] : biasV[c - 2 * DMODEL];
    else bv = bias[c];
    bool tovT = (vTout != nullptr) && (c >= 2 * DMODEL);
    int hd = c - 2 * DMODEL;   // h*64+d when tovT
    #pragma unroll
    for (int m = 0; m < 4; ++m) {
      #pragma unroll
      for (int r = 0; r < 4; ++r) {
        float val = acc[m][n][r] + bv;
        if (relu) val = fmaxf(val, 0.f);
        int mr = crow0 + m * 16 + r;
        if (tovT) {
          vTout[((size_t)((mr >> 9) * NHEAD + (hd >> 6)) * HDIM + (hd & 63)) * SEQ + (mr & 511)] = f2bf(val);
        } else if (out_bf16) {
          ((unsigned short*)Cout)[(size_t)mr * N + c] = f2bf(val);
        } else {
          ((float*)Cout)[(size_t)mr * N + c] = val;
        }
      }
    }
  }
}

// ---------------------------------------------------------------------------
// MFMA flash attention, KVBLK=128: one block per (b, h, 64-query tile); 4
// waves; each wave owns 16 q-rows. Q in registers; K [128][64] and V^T
// [64][128] staged swizzled via global_load_lds (slot = g ^ (row&7), XOR on
// low 3 bits). 4 K-tiles of 128 -> half the barriers/softmax passes of r6.
// ---------------------------------------------------------------------------
#define KT 128
__global__ __launch_bounds__(256) void attention_mfma_kernel(
    const unsigned short* __restrict__ qkv,  // [NTOK][2304] bf16 (Q|K|V)
    const unsigned short* __restrict__ vT,   // [(b*H+h)*64+d][SEQ] bf16
    const int* __restrict__ mask,            // [B][SEQ]
    unsigned short* __restrict__ out) {      // [NTOK][768] bf16
  unsigned orig = blockIdx.x;
  unsigned blk = (orig & 7) * (gridDim.x >> 3) + (orig >> 3);
  int qt0 = (blk % (SEQ / 64)) * 64;
  int h = (blk / (SEQ / 64)) % NHEAD;
  int b = blk / ((SEQ / 64) * NHEAD);
  int tid = threadIdx.x, lane = tid & 63, wave = tid >> 6;

  __shared__ unsigned short Ks[KT * 64];      // [key][dimgrp ^ (key&7)]
  __shared__ unsigned short Vs[64 * KT];      // [d][keygrp ^low3 (d&7)]
  __shared__ unsigned short Ps[4][16 * 136];  // per-wave P[q][key], stride 136
  __shared__ int msk_s[SEQ];

  if (tid < SEQ / 4) *(int4*)&msk_s[tid * 4] = *(const int4*)&mask[b * SEQ + tid * 4];

  int qrow = qt0 + wave * 16 + (lane & 15);
  const unsigned short* qp = qkv + (size_t)(b * SEQ + qrow) * QKVN + h * HDIM + (lane >> 4) * 8;
  short8 qf0 = *(const short8*)qp;
  short8 qf1 = *(const short8*)(qp + 32);

  float m_r[4], l_r[4];
  f32x4 acc_o[4];
  #pragma unroll
  for (int r = 0; r < 4; ++r) { m_r[r] = -3.0e38f; l_r[r] = 0.f; }
  #pragma unroll
  for (int n = 0; n < 4; ++n) acc_o[n] = (f32x4){0.f, 0.f, 0.f, 0.f};

  for (int kt = 0; kt < SEQ / KT; ++kt) {
    __syncthreads();
    // stage: Ks 128x8 chunks, Vs 64x16 chunks (1024 each; 4 per thread)
    #pragma unroll
    for (int it = 0; it < 4; ++it) {
      int ck = it * 256 + tid;
      int krow = ck >> 3, kg = ck & 7;
      gload16(qkv + (size_t)(b * SEQ + kt * KT + krow) * QKVN + DMODEL + h * HDIM + ((kg ^ (krow & 7)) * 8),
              Ks + ck * 8);
      int vrow = ck >> 4, vg = ck & 15;
      gload16(vT + (size_t)((b * NHEAD + h) * HDIM + vrow) * SEQ + kt * KT + ((vg ^ (vrow & 7)) * 8),
              Vs + ck * 8);
    }
    __syncthreads();

    // ---- S = Q K^T  (8 key-fragments of 16) ----
    f32x4 acc_s[8];
    #pragma unroll
    for (int nf = 0; nf < 8; ++nf) acc_s[nf] = (f32x4){0.f, 0.f, 0.f, 0.f};
    #pragma unroll
    for (int nf = 0; nf < 8; ++nf) {
      int rb = nf * 16 + (lane & 15);
      int G = lane >> 4;
      short8 kf0 = *(const short8*)(Ks + rb * 64 + ((G ^ (rb & 7)) * 8));
      short8 kf1 = *(const short8*)(Ks + rb * 64 + (((G + 4) ^ (rb & 7)) * 8));
      acc_s[nf] = __builtin_amdgcn_mfma_f32_16x16x32_bf16(qf0, kf0, acc_s[nf], 0, 0, 0);
      acc_s[nf] = __builtin_amdgcn_mfma_f32_16x16x32_bf16(qf1, kf1, acc_s[nf], 0, 0, 0);
    }

    // ---- online softmax (scale+mask in place, then exp) ----
    float rmax[4];
    #pragma unroll
    for (int r = 0; r < 4; ++r) rmax[r] = -3.0e38f;
    #pragma unroll
    for (int nf = 0; nf < 8; ++nf) {
      int msk = msk_s[kt * KT + nf * 16 + (lane & 15)];
      #pragma unroll
      for (int r = 0; r < 4; ++r) {
        float s = acc_s[nf][r] * 0.125f;
        if (msk == 0) s = -1e9f;
        acc_s[nf][r] = s;
        rmax[r] = fmaxf(rmax[r], s);
      }
    }
    #pragma unroll
    for (int r = 0; r < 4; ++r) {
      rmax[r] = fmaxf(rmax[r], __shfl_xor(rmax[r], 1));
      rmax[r] = fmaxf(rmax[r], __shfl_xor(rmax[r], 2));
      rmax[r] = fmaxf(rmax[r], __shfl_xor(rmax[r], 4));
      rmax[r] = fmaxf(rmax[r], __shfl_xor(rmax[r], 8));
    }
    float corr[4], psum[4];
    #pragma unroll
    for (int r = 0; r < 4; ++r) {
      float mn = fmaxf(m_r[r], rmax[r]);
      corr[r] = expf(m_r[r] - mn);
      m_r[r] = mn;
      psum[r] = 0.f;
    }
    #pragma unroll
    for (int nf = 0; nf < 8; ++nf) {
      #pragma unroll
      for (int r = 0; r < 4; ++r) {
        float e = expf(acc_s[nf][r] - m_r[r]);
        psum[r] += e;
        Ps[wave][((lane >> 4) * 4 + r) * 136 + nf * 16 + (lane & 15)] = f2bf(e);
      }
    }
    #pragma unroll
    for (int r = 0; r < 4; ++r) {
      psum[r] += __shfl_xor(psum[r], 1);
      psum[r] += __shfl_xor(psum[r], 2);
      psum[r] += __shfl_xor(psum[r], 4);
      psum[r] += __shfl_xor(psum[r], 8);
      l_r[r] = l_r[r] * corr[r] + psum[r];
    }
    #pragma unroll
    for (int n = 0; n < 4; ++n)
      #pragma unroll
      for (int r = 0; r < 4; ++r)
        acc_o[n][r] *= corr[r];

    // ---- O += P V  (P rows q=lane&15; key chunks kh*32) ----
    short8 pa[4];
    #pragma unroll
    for (int kh = 0; kh < 4; ++kh)
      pa[kh] = *(const short8*)(&Ps[wave][(lane & 15) * 136 + kh * 32 + (lane >> 4) * 8]);
    #pragma unroll
    for (int nd = 0; nd < 4; ++nd) {
      int rb = nd * 16 + (lane & 15);
      #pragma unroll
      for (int kh = 0; kh < 4; ++kh) {
        int G = (lane >> 4) + kh * 4;
        short8 vf = *(const short8*)(Vs + rb * KT + ((G ^ (rb & 7)) * 8));
        acc_o[nd] = __builtin_amdgcn_mfma_f32_16x16x32_bf16(pa[kh], vf, acc_o[nd], 0, 0, 0);
      }
    }
  }

  #pragma unroll
  for (int r = 0; r < 4; ++r) {
    float inv = 1.0f / l_r[r];
    int row = qt0 + wave * 16 + (lane >> 4) * 4 + r;
    unsigned short* op = out + (size_t)(b * SEQ + row) * DMODEL + h * HDIM + (lane & 15);
    #pragma unroll
    for (int n = 0; n < 4; ++n)
      op[n * 16] = f2bf(acc_o[n][r] * inv);
  }
}

// ---------------------------------------------------------------------------
// LayerNorm, wave-per-token (no LDS, no barriers). 4 tokens per 256-thr block.
// x f32 (+optional bf16 residual o); writes f32 out and optional bf16 outb.
// ---------------------------------------------------------------------------
__global__ __launch_bounds__(256) void ln_kernel(
    const float* __restrict__ x, const unsigned short* __restrict__ o,
    float* __restrict__ out, unsigned short* __restrict__ outb,
    const float* __restrict__ g, const float* __restrict__ bta) {
  int lane = threadIdx.x & 63, wave = threadIdx.x >> 6;
  int n = blockIdx.x * 4 + wave;
  size_t base = (size_t)n * DMODEL;

  float v[12];
  float sum = 0.f;
  #pragma unroll
  for (int c = 0; c < 3; ++c) {
    int off = c * 256 + lane * 4;
    float4 xv = *(const float4*)(x + base + off);
    v[c * 4 + 0] = xv.x; v[c * 4 + 1] = xv.y;
    v[c * 4 + 2] = xv.z; v[c * 4 + 3] = xv.w;
    if (o) {
      ushortx4 ov = *(const ushortx4*)(o + base + off);
      #pragma unroll
      for (int j = 0; j < 4; ++j) v[c * 4 + j] += bf2f(ov[j]);
    }
    #pragma unroll
    for (int j = 0; j < 4; ++j) sum += v[c * 4 + j];
  }
  #pragma unroll
  for (int s = 1; s < 64; s <<= 1) sum += __shfl_xor(sum, s);
  float mu = sum * (1.0f / DMODEL);
  float var = 0.f;
  #pragma unroll
  for (int i = 0; i < 12; ++i) {
    float d = v[i] - mu;
    var += d * d;
  }
  #pragma unroll
  for (int s = 1; s < 64; s <<= 1) var += __shfl_xor(var, s);
  float rstd = rsqrtf(var * (1.0f / DMODEL) + 1e-5f);

  #pragma unroll
  for (int c = 0; c < 3; ++c) {
    int off = c * 256 + lane * 4;
    float4 gv = *(const float4*)(g + off);
    float4 bv = *(const float4*)(bta + off);
    float4 r;
    r.x = (v[c * 4 + 0] - mu) * rstd * gv.x + bv.x;
    r.y = (v[c * 4 + 1] - mu) * rstd * gv.y + bv.y;
    r.z = (v[c * 4 + 2] - mu) * rstd * gv.z + bv.z;
    r.w = (v[c * 4 + 3] - mu) * rstd * gv.w + bv.w;
    *(float4*)(out + base + off) = r;
    if (outb) {
      ushortx4 rb;
      rb[0] = f2bf(r.x); rb[1] = f2bf(r.y); rb[2] = f2bf(r.z); rb[3] = f2bf(r.w);
      *(ushortx4*)(outb + base + off) = rb;
    }
  }
}

// ---------------------------------------------------------------------------
// Mean-pool, stage 1: 8 sequence chunks of 64 rows -> partial[chunk][b][d]
// grid = 8 * B * (D/256) = 192 blocks
// ---------------------------------------------------------------------------
__global__ __launch_bounds__(256) void pool_part_kernel(
    const float* __restrict__ xin, float* __restrict__ partial) {
  int blk = blockIdx.x;
  int chunk = blk / (BATCH * 3);
  int rem = blk % (BATCH * 3);
  int b = rem / 3, dc = rem % 3;
  int d = dc * 256 + threadIdx.x;
  float s_ = 0.f;
  for (int s = chunk * 64; s < chunk * 64 + 64; ++s)
    s_ += xin[(size_t)(b * SEQ + s) * DMODEL + d];
  partial[((size_t)chunk * BATCH + b) * DMODEL + d] = s_;
}

// ---------------------------------------------------------------------------
// Classifier: reduce 8 pool partials, logits = pooled @ Wfc + bfc, log_softmax
// ---------------------------------------------------------------------------
__global__ __launch_bounds__(256) void classifier_kernel(
    const float* __restrict__ partial, const float* __restrict__ Wfc,
    const float* __restrict__ bfc, float* __restrict__ out) {
  int b = blockIdx.x;
  int t = threadIdx.x;
  __shared__ float s0[256], s1[256];
  float acc0 = 0.f, acc1 = 0.f;
  for (int d = t; d < DMODEL; d += 256) {
    float p = 0.f;
    #pragma unroll
    for (int c = 0; c < 8; ++c)
      p += partial[((size_t)c * BATCH + b) * DMODEL + d];
    p *= (1.0f / SEQ);
    acc0 += p * Wfc[d * NCLS + 0];
    acc1 += p * Wfc[d * NCLS + 1];
  }
  s0[t] = acc0; s1[t] = acc1; __syncthreads();
  for (int off = 128; off; off >>= 1) {
    if (t < off) { s0[t] += s0[t + off]; s1[t] += s1[t + off]; }
    __syncthreads();
  }
  if (t == 0) {
    float l0 = s0[0] + bfc[0], l1 = s1[0] + bfc[1];
    float m = fmaxf(l0, l1);
    float lse = m + logf(expf(l0 - m) + expf(l1 - m));
    out[b * NCLS + 0] = l0 - lse;
    out[b * NCLS + 1] = l1 - lse;
  }
}

// ---------------------------------------------------------------------------
extern "C" void kernel_launch(void* const* d_in, const int* in_sizes, int n_in,
                              void* d_out, int out_size, void* d_ws, size_t ws_size,
                              hipStream_t stream) {
  const int*   text  = (const int*)d_in[0];
  const int*   mask  = (const int*)d_in[1];
  const float* emb   = (const float*)d_in[2];
  const float* Wq    = (const float*)d_in[3];
  const float* bq    = (const float*)d_in[4];
  const float* Wk    = (const float*)d_in[5];
  const float* bk    = (const float*)d_in[6];
  const float* Wv    = (const float*)d_in[7];
  const float* bv    = (const float*)d_in[8];
  const float* Wo    = (const float*)d_in[9];
  const float* bo    = (const float*)d_in[10];
  const float* W1    = (const float*)d_in[11];
  const float* b1    = (const float*)d_in[12];
  const float* W2    = (const float*)d_in[13];
  const float* b2    = (const float*)d_in[14];
  const float* ln1_g = (const float*)d_in[15];
  const float* ln1_b = (const float*)d_in[16];
  const float* ln2_g = (const float*)d_in[17];
  const float* ln2_b = (const float*)d_in[18];
  const float* lnf_g = (const float*)d_in[19];
  const float* lnf_b = (const float*)d_in[20];
  const float* Wfc   = (const float*)d_in[21];
  const float* bfc   = (const float*)d_in[22];

  const size_t ND = (size_t)NTOK * DMODEL;
  const size_t NF = (size_t)NTOK * FFDIM;
  const size_t WDD = (size_t)DMODEL * DMODEL;
  const size_t WDF = (size_t)DMODEL * FFDIM;

  float* xf      = (float*)d_ws;                  // [N,D] f32 residual
  float* partial = xf + ND;                       // [8][B][D] pool partials
  unsigned short* xb   = (unsigned short*)(partial + 8 * BATCH * DMODEL);
  unsigned short* qkvb = xb + ND;                 // [N,2304]; also o/ffn2 out
  unsigned short* vTb  = qkvb + (size_t)NTOK * QKVN;  // [B*H*64][SEQ]
  unsigned short* aob  = vTb + ND;                // [N,D] attention out
  unsigned short* h1b  = aob + ND;                // [N,FF]
  unsigned short* wqkvT = h1b + NF;               // 4 x [2304][768]
  unsigned short* woT  = wqkvT + 4 * 3 * WDD;     // 4 x [768][768]
  unsigned short* w1T  = woT + 4 * WDD;           // 4 x [FF][D]
  unsigned short* w2T  = w1T + 4 * WDF;           // 4 x [D][FF]
  unsigned short* ob   = qkvb;                    // alias: o-proj/ffn2 output

  dim3 gD64(DMODEL / 64, NTOK / BM);   // (12, 32) = 384 blocks, TBN=64
  dim3 gQKV(QKVN / 128, NTOK / BM);    // (18, 32) = 576 blocks, TBN=128
  dim3 gF(FFDIM / 128, NTOK / BM);     // (24, 32) = 768 blocks, TBN=128

  embed_kernel<<<NTOK, 256, 0, stream>>>(text, emb, xf, xb);
  wconv_all_kernel<<<4 * 1728, 256, 0, stream>>>(
      Wq, Wk, Wv, Wo, W1, W2, wqkvT, woT, w1T, w2T);

  for (int l = 0; l < LAYERS; ++l) {
    // fused QKV projection (V written transposed to vTb)
    gemm_mfma_kernel<128><<<gQKV, 256, 0, stream>>>(
        xb, wqkvT + (size_t)l * 3 * WDD, bq + l * DMODEL, bk + l * DMODEL,
        bv + l * DMODEL, qkvb, vTb, NTOK, QKVN, DMODEL, 1, 0);

    attention_mfma_kernel<<<BATCH * NHEAD * (SEQ / 64), 256, 0, stream>>>(
        qkvb, vTb, mask, aob);

    gemm_mfma_kernel<64><<<gD64, 256, 0, stream>>>(
        aob, woT + (size_t)l * WDD, bo + l * DMODEL, nullptr, nullptr,
        ob, nullptr, NTOK, DMODEL, DMODEL, 1, 0);
    ln_kernel<<<NTOK / 4, 256, 0, stream>>>(xf, ob, xf, xb,
                                            ln1_g + l * DMODEL, ln1_b + l * DMODEL);
    gemm_mfma_kernel<128><<<gF, 256, 0, stream>>>(
        xb, w1T + (size_t)l * WDF, b1 + l * FFDIM, nullptr, nullptr,
        h1b, nullptr, NTOK, FFDIM, DMODEL, 1, 1);
    gemm_mfma_kernel<64><<<gD64, 256, 0, stream>>>(
        h1b, w2T + (size_t)l * WDF, b2 + l * DMODEL, nullptr, nullptr,
        ob, nullptr, NTOK, DMODEL, FFDIM, 1, 0);
    ln_kernel<<<NTOK / 4, 256, 0, stream>>>(xf, ob, xf, xb,
                                            ln2_g + l * DMODEL, ln2_b + l * DMODEL);
  }

  // final LN in-place on xf, then pool partials + classify
  ln_kernel<<<NTOK / 4, 256, 0, stream>>>(xf, nullptr, xf, nullptr, lnf_g, lnf_b);
  pool_part_kernel<<<8 * BATCH * 3, 256, 0, stream>>>(xf, partial);
  classifier_kernel<<<BATCH, 256, 0, stream>>>(partial, Wfc, bfc, (float*)d_out);
}

// Round 8
// 679.081 us; speedup vs baseline: 15.0218x; 1.0141x over previous
//
#include <hip/hip_runtime.h>
#include <hip/hip_bf16.h>
#include <math.h>

// Problem constants (match reference)
#define LAYERS 4
#define DMODEL 768
#define NHEAD 12
#define HDIM 64
#define FFDIM 3072
#define VOCAB 32000
#define NCLS 2
#define BATCH 8
#define SEQ 512
#define NTOK (BATCH * SEQ)   // 4096
#define QKVN (3 * DMODEL)    // 2304

typedef __attribute__((ext_vector_type(8))) short short8;      // 8 bf16 (4 VGPR)
typedef __attribute__((ext_vector_type(8))) unsigned short ushortx8;
typedef __attribute__((ext_vector_type(4))) unsigned short ushortx4;
typedef __attribute__((ext_vector_type(4))) float f32x4;

__device__ __forceinline__ float bf2f(unsigned short u) {
  return __uint_as_float(((unsigned)u) << 16);
}
__device__ __forceinline__ unsigned short f2bf(float x) {
  unsigned u = __float_as_uint(x);
  unsigned r = (u + 0x7fffu + ((u >> 16) & 1u)) >> 16;   // RNE
  return (unsigned short)r;
}

// async global->LDS, 16 bytes per lane (lds ptr = wave-uniform base + lane*16)
__device__ __forceinline__ void gload16(const void* gp, void* lp) {
  __builtin_amdgcn_global_load_lds(
      (const __attribute__((address_space(1))) void*)((unsigned long long)gp),
      (__attribute__((address_space(3))) void*)((unsigned int)(unsigned long long)lp),
      16, 0, 0);
}

// ---------------------------------------------------------------------------
// Embedding + positional encoding; writes f32 x (residual) and bf16 xb
// ---------------------------------------------------------------------------
__global__ __launch_bounds__(256) void embed_kernel(
    const int* __restrict__ text, const float* __restrict__ emb,
    float* __restrict__ x, unsigned short* __restrict__ xb) {
  int n = blockIdx.x;
  int t = threadIdx.x;
  int tok = text[n];
  int s = n % SEQ;
  const float sqrtD = 27.712812921102035f;
  const float nlog10k_over_d = -9.210340371976184f / 768.0f;
  #pragma unroll
  for (int i = 0; i < 3; ++i) {
    int d = t + i * 256;
    int j = d >> 1;
    float freq = expf((float)(2 * j) * nlog10k_over_d);
    float ang = (float)s * freq;
    float pe = (d & 1) ? cosf(ang) : sinf(ang);
    float val = emb[(size_t)tok * DMODEL + d] * sqrtD + pe;
    x[(size_t)n * DMODEL + d] = val;
    xb[(size_t)n * DMODEL + d] = f2bf(val);
  }
}

// ---------------------------------------------------------------------------
// Weight convert+transpose tile body: W[K][N] f32 -> Wt[N][K] bf16, 64x64 tile
// ---------------------------------------------------------------------------
__device__ __forceinline__ void wconv_tile(
    const float* __restrict__ W, unsigned short* __restrict__ Wt,
    int K, int N, int k0, int n0, int tid, float (*t)[65]) {
  {
    int r = tid >> 2, c4 = (tid & 3) * 16;
    #pragma unroll
    for (int j = 0; j < 4; ++j) {
      float4 vv = *(const float4*)(W + (size_t)(k0 + r) * N + n0 + c4 + j * 4);
      t[r][c4 + j * 4 + 0] = vv.x; t[r][c4 + j * 4 + 1] = vv.y;
      t[r][c4 + j * 4 + 2] = vv.z; t[r][c4 + j * 4 + 3] = vv.w;
    }
  }
  __syncthreads();
  {
    int n = tid >> 2, k4 = (tid & 3) * 16;
    ushortx8 u0, u1;
    #pragma unroll
    for (int j = 0; j < 8; ++j) u0[j] = f2bf(t[k4 + j][n]);
    #pragma unroll
    for (int j = 0; j < 8; ++j) u1[j] = f2bf(t[k4 + 8 + j][n]);
    *(ushortx8*)(Wt + (size_t)(n0 + n) * K + k0 + k4) = u0;
    *(ushortx8*)(Wt + (size_t)(n0 + n) * K + k0 + k4 + 8) = u1;
  }
}

// All 4 layers' 6 weight matrices in ONE dispatch. 4 x 1728 = 6912 blocks.
// Per layer: [0,576): wq/wk/wv/wo (144 tiles each), [576,1152): w1, [1152,1728): w2
__global__ __launch_bounds__(256) void wconv_all_kernel(
    const float* __restrict__ Wq, const float* __restrict__ Wk,
    const float* __restrict__ Wv, const float* __restrict__ Wo,
    const float* __restrict__ W1, const float* __restrict__ W2,
    unsigned short* __restrict__ wqkvT, unsigned short* __restrict__ woT,
    unsigned short* __restrict__ w1T, unsigned short* __restrict__ w2T) {
  __shared__ float t[64][65];
  const size_t WDD = (size_t)DMODEL * DMODEL;
  const size_t WDF = (size_t)DMODEL * FFDIM;
  int l = blockIdx.x / 1728;
  int blk = blockIdx.x % 1728;
  const float* W; unsigned short* Wt; int K, N, tx, ty;
  if (blk < 576) {
    int region = blk / 144, r = blk % 144;
    tx = r % 12; ty = r / 12; K = DMODEL; N = DMODEL;
    W = (region == 0) ? (Wq + l * WDD) : (region == 1) ? (Wk + l * WDD)
      : (region == 2) ? (Wv + l * WDD) : (Wo + l * WDD);
    Wt = (region < 3) ? (wqkvT + (size_t)l * 3 * WDD + (size_t)region * WDD)
                      : (woT + (size_t)l * WDD);
  } else if (blk < 1152) {
    int r = blk - 576; tx = r % 48; ty = r / 48; K = DMODEL; N = FFDIM;
    W = W1 + l * WDF; Wt = w1T + (size_t)l * WDF;
  } else {
    int r = blk - 1152; tx = r % 12; ty = r / 12; K = FFDIM; N = DMODEL;
    W = W2 + l * WDF; Wt = w2T + (size_t)l * WDF;
  }
  wconv_tile(W, Wt, K, N, ty * 64, tx * 64, threadIdx.x, t);
}

// ---------------------------------------------------------------------------
// bf16 MFMA GEMM: C[M][N] = A[M][K] @ Bt[N][K]^T + bias
// BM=128 x TBN tile, BK=64, 4 waves. TBN=128: 4x4 frags; TBN=64: 4x2 frags.
// T3 2-phase double-buffer: STAGE(next) issued BEFORE compute(cur); one
// __syncthreads() (vmcnt0+barrier) per K-step -> loads hide under MFMA.
// XCD-aware bijective block swizzle (grid must be a multiple of 8).
//
// LDS swizzle invariant (both sides): staging stores global k-group g of row
// r at slot g ^ (r&7); fragment rows have r&7 == lane&7, and lane needs
// global group (lane>>4) + kh*4, so the read slot is
//   gs = (lane>>4) ^ (lane&7) ^ (kh*4)      [VERIFIED round 4/6; do NOT
// algebraically "simplify" -- round 5 broke correctness that way.]
// ---------------------------------------------------------------------------
#define BM 128
#define BK 64
template <int TBN>
__global__ __launch_bounds__(256, 2) void gemm_mfma_kernel(
    const unsigned short* __restrict__ A,    // [M][K] bf16
    const unsigned short* __restrict__ Bt,   // [N][K] bf16
    const float* __restrict__ bias,          // [N] (or Q region)
    const float* __restrict__ biasK,         // K region (QKV mode)
    const float* __restrict__ biasV,         // V region (QKV mode)
    void* __restrict__ Cout,                 // [M][N] f32 or bf16
    unsigned short* __restrict__ vTout,      // QKV mode V^T output
    int M, int N, int K, int out_bf16, int relu) {
  constexpr int NF = TBN / 32;               // n-fragments per wave
  __shared__ unsigned short As[2][BM * BK];  // double-buffered
  __shared__ unsigned short Bs[2][TBN * BK];

  const int tid = threadIdx.x;
  const int lane = tid & 63;
  const int wave = tid >> 6;

  // XCD swizzle: hardware block orig -> logical tile swz (x-first chunks)
  unsigned nwg = gridDim.x * gridDim.y;
  unsigned orig = blockIdx.y * gridDim.x + blockIdx.x;
  unsigned swz = (orig & 7) * (nwg >> 3) + (orig >> 3);
  const int m0 = (swz / gridDim.x) * BM;
  const int n0 = (swz % gridDim.x) * TBN;

  const int wrow = (wave >> 1) * 64;
  const int wcol = (wave & 1) * (TBN / 2);

  const int lrow = lane >> 3;
  const int kgrp = (lane & 7) ^ lrow;

  const unsigned short* Ab = A  + (size_t)(m0 + 32 * wave + lrow) * K + kgrp * 8;
  const unsigned short* Bb = Bt + (size_t)(n0 + (TBN / 4) * wave + lrow) * K + kgrp * 8;
  const int AsWoff = wave * 2048 + lane * 8;
  const int BsWoff = wave * (TBN / 4) * BK + lane * 8;

  f32x4 acc[4][NF];
  #pragma unroll
  for (int m = 0; m < 4; ++m)
    #pragma unroll
    for (int n = 0; n < NF; ++n)
      acc[m][n] = (f32x4){0.f, 0.f, 0.f, 0.f};

  const int g0 = (lane >> 4) ^ (lane & 7);

  // ---- prologue: stage k0=0 into buffer 0 ----
  #pragma unroll
  for (int i = 0; i < 4; ++i)
    gload16(Ab + (size_t)(8 * i) * K, As[0] + AsWoff + i * 512);
  #pragma unroll
  for (int i = 0; i < NF; ++i)
    gload16(Bb + (size_t)(8 * i) * K, Bs[0] + BsWoff + i * 512);
  __syncthreads();

  int cur = 0;
  for (int k0 = 0; k0 < K; k0 += BK) {
    // issue next tile's loads into the other buffer (overlap with compute)
    if (k0 + BK < K) {
      const int nxt = cur ^ 1;
      #pragma unroll
      for (int i = 0; i < 4; ++i)
        gload16(Ab + (size_t)(8 * i) * K + k0 + BK, As[nxt] + AsWoff + i * 512);
      #pragma unroll
      for (int i = 0; i < NF; ++i)
        gload16(Bb + (size_t)(8 * i) * K + k0 + BK, Bs[nxt] + BsWoff + i * 512);
    }
    // compute current buffer
    #pragma unroll
    for (int kh = 0; kh < 2; ++kh) {
      const int gs = g0 ^ (kh * 4);
      short8 a[4], b[NF];
      #pragma unroll
      for (int m = 0; m < 4; ++m) {
        int r = wrow + m * 16 + (lane & 15);
        a[m] = *(const short8*)(As[cur] + r * 64 + gs * 8);
      }
      #pragma unroll
      for (int n = 0; n < NF; ++n) {
        int r = wcol + n * 16 + (lane & 15);
        b[n] = *(const short8*)(Bs[cur] + r * 64 + gs * 8);
      }
      #pragma unroll
      for (int m = 0; m < 4; ++m)
        #pragma unroll
        for (int n = 0; n < NF; ++n)
          acc[m][n] = __builtin_amdgcn_mfma_f32_16x16x32_bf16(a[m], b[n], acc[m][n], 0, 0, 0);
    }
    __syncthreads();   // drains next-tile loads; syncs buffer handoff
    cur ^= 1;
  }

  const int crow0 = m0 + wrow + (lane >> 4) * 4;
  const int ccol0 = n0 + wcol + (lane & 15);
  #pragma unroll
  for (int n = 0; n < NF; ++n) {
    int c = ccol0 + n * 16;
    float bv;
    if (vTout) bv = (c < DMODEL) ? bias[c]
                  : (c < 2 * DMODEL) ? biasK[c - DMODEL] : biasV[c - 2 * DMODEL];
    else bv = bias[c];
    bool tovT = (vTout != nullptr) && (c >= 2 * DMODEL);
    int hd = c - 2 * DMODEL;   // h*64+d when tovT
    #pragma unroll
    for (int m = 0; m < 4; ++m) {
      #pragma unroll
      for (int r = 0; r < 4; ++r) {
        float val = acc[m][n][r] + bv;
        if (relu) val = fmaxf(val, 0.f);
        int mr = crow0 + m * 16 + r;
        if (tovT) {
          vTout[((size_t)((mr >> 9) * NHEAD + (hd >> 6)) * HDIM + (hd & 63)) * SEQ + (mr & 511)] = f2bf(val);
        } else if (out_bf16) {
          ((unsigned short*)Cout)[(size_t)mr * N + c] = f2bf(val);
        } else {
          ((float*)Cout)[(size_t)mr * N + c] = val;
        }
      }
    }
  }
}

// ---------------------------------------------------------------------------
// MFMA flash attention, KVBLK=128: one block per (b, h, 64-query tile); 4
// waves; each wave owns 16 q-rows. Q in registers; K [128][64] and V^T
// [64][128] staged swizzled via global_load_lds (slot = g ^ (row&7), XOR on
// low 3 bits).
// ---------------------------------------------------------------------------
#define KT 128
__global__ __launch_bounds__(256) void attention_mfma_kernel(
    const unsigned short* __restrict__ qkv,  // [NTOK][2304] bf16 (Q|K|V)
    const unsigned short* __restrict__ vT,   // [(b*H+h)*64+d][SEQ] bf16
    const int* __restrict__ mask,            // [B][SEQ]
    unsigned short* __restrict__ out) {      // [NTOK][768] bf16
  unsigned orig = blockIdx.x;
  unsigned blk = (orig & 7) * (gridDim.x >> 3) + (orig >> 3);
  int qt0 = (blk % (SEQ / 64)) * 64;
  int h = (blk / (SEQ / 64)) % NHEAD;
  int b = blk / ((SEQ / 64) * NHEAD);
  int tid = threadIdx.x, lane = tid & 63, wave = tid >> 6;

  __shared__ unsigned short Ks[KT * 64];      // [key][dimgrp ^ (key&7)]
  __shared__ unsigned short Vs[64 * KT];      // [d][keygrp ^low3 (d&7)]
  __shared__ unsigned short Ps[4][16 * 136];  // per-wave P[q][key], stride 136
  __shared__ int msk_s[SEQ];

  if (tid < SEQ / 4) *(int4*)&msk_s[tid * 4] = *(const int4*)&mask[b * SEQ + tid * 4];

  int qrow = qt0 + wave * 16 + (lane & 15);
  const unsigned short* qp = qkv + (size_t)(b * SEQ + qrow) * QKVN + h * HDIM + (lane >> 4) * 8;
  short8 qf0 = *(const short8*)qp;
  short8 qf1 = *(const short8*)(qp + 32);

  float m_r[4], l_r[4];
  f32x4 acc_o[4];
  #pragma unroll
  for (int r = 0; r < 4; ++r) { m_r[r] = -3.0e38f; l_r[r] = 0.f; }
  #pragma unroll
  for (int n = 0; n < 4; ++n) acc_o[n] = (f32x4){0.f, 0.f, 0.f, 0.f};

  for (int kt = 0; kt < SEQ / KT; ++kt) {
    __syncthreads();
    // stage: Ks 128x8 chunks, Vs 64x16 chunks (1024 each; 4 per thread)
    #pragma unroll
    for (int it = 0; it < 4; ++it) {
      int ck = it * 256 + tid;
      int krow = ck >> 3, kg = ck & 7;
      gload16(qkv + (size_t)(b * SEQ + kt * KT + krow) * QKVN + DMODEL + h * HDIM + ((kg ^ (krow & 7)) * 8),
              Ks + ck * 8);
      int vrow = ck >> 4, vg = ck & 15;
      gload16(vT + (size_t)((b * NHEAD + h) * HDIM + vrow) * SEQ + kt * KT + ((vg ^ (vrow & 7)) * 8),
              Vs + ck * 8);
    }
    __syncthreads();

    // ---- S = Q K^T  (8 key-fragments of 16) ----
    f32x4 acc_s[8];
    #pragma unroll
    for (int nf = 0; nf < 8; ++nf) acc_s[nf] = (f32x4){0.f, 0.f, 0.f, 0.f};
    #pragma unroll
    for (int nf = 0; nf < 8; ++nf) {
      int rb = nf * 16 + (lane & 15);
      int G = lane >> 4;
      short8 kf0 = *(const short8*)(Ks + rb * 64 + ((G ^ (rb & 7)) * 8));
      short8 kf1 = *(const short8*)(Ks + rb * 64 + (((G + 4) ^ (rb & 7)) * 8));
      acc_s[nf] = __builtin_amdgcn_mfma_f32_16x16x32_bf16(qf0, kf0, acc_s[nf], 0, 0, 0);
      acc_s[nf] = __builtin_amdgcn_mfma_f32_16x16x32_bf16(qf1, kf1, acc_s[nf], 0, 0, 0);
    }

    // ---- online softmax (scale+mask in place, then exp) ----
    float rmax[4];
    #pragma unroll
    for (int r = 0; r < 4; ++r) rmax[r] = -3.0e38f;
    #pragma unroll
    for (int nf = 0; nf < 8; ++nf) {
      int msk = msk_s[kt * KT + nf * 16 + (lane & 15)];
      #pragma unroll
      for (int r = 0; r < 4; ++r) {
        float s = acc_s[nf][r] * 0.125f;
        if (msk == 0) s = -1e9f;
        acc_s[nf][r] = s;
        rmax[r] = fmaxf(rmax[r], s);
      }
    }
    #pragma unroll
    for (int r = 0; r < 4; ++r) {
      rmax[r] = fmaxf(rmax[r], __shfl_xor(rmax[r], 1));
      rmax[r] = fmaxf(rmax[r], __shfl_xor(rmax[r], 2));
      rmax[r] = fmaxf(rmax[r], __shfl_xor(rmax[r], 4));
      rmax[r] = fmaxf(rmax[r], __shfl_xor(rmax[r], 8));
    }
    float corr[4], psum[4];
    #pragma unroll
    for (int r = 0; r < 4; ++r) {
      float mn = fmaxf(m_r[r], rmax[r]);
      corr[r] = expf(m_r[r] - mn);
      m_r[r] = mn;
      psum[r] = 0.f;
    }
    #pragma unroll
    for (int nf = 0; nf < 8; ++nf) {
      #pragma unroll
      for (int r = 0; r < 4; ++r) {
        float e = expf(acc_s[nf][r] - m_r[r]);
        psum[r] += e;
        Ps[wave][((lane >> 4) * 4 + r) * 136 + nf * 16 + (lane & 15)] = f2bf(e);
      }
    }
    #pragma unroll
    for (int r = 0; r < 4; ++r) {
      psum[r] += __shfl_xor(psum[r], 1);
      psum[r] += __shfl_xor(psum[r], 2);
      psum[r] += __shfl_xor(psum[r], 4);
      psum[r] += __shfl_xor(psum[r], 8);
      l_r[r] = l_r[r] * corr[r] + psum[r];
    }
    #pragma unroll
    for (int n = 0; n < 4; ++n)
      #pragma unroll
      for (int r = 0; r < 4; ++r)
        acc_o[n][r] *= corr[r];

    // ---- O += P V  (P rows q=lane&15; key chunks kh*32) ----
    short8 pa[4];
    #pragma unroll
    for (int kh = 0; kh < 4; ++kh)
      pa[kh] = *(const short8*)(&Ps[wave][(lane & 15) * 136 + kh * 32 + (lane >> 4) * 8]);
    #pragma unroll
    for (int nd = 0; nd < 4; ++nd) {
      int rb = nd * 16 + (lane & 15);
      #pragma unroll
      for (int kh = 0; kh < 4; ++kh) {
        int G = (lane >> 4) + kh * 4;
        short8 vf = *(const short8*)(Vs + rb * KT + ((G ^ (rb & 7)) * 8));
        acc_o[nd] = __builtin_amdgcn_mfma_f32_16x16x32_bf16(pa[kh], vf, acc_o[nd], 0, 0, 0);
      }
    }
  }

  #pragma unroll
  for (int r = 0; r < 4; ++r) {
    float inv = 1.0f / l_r[r];
    int row = qt0 + wave * 16 + (lane >> 4) * 4 + r;
    unsigned short* op = out + (size_t)(b * SEQ + row) * DMODEL + h * HDIM + (lane & 15);
    #pragma unroll
    for (int n = 0; n < 4; ++n)
      op[n * 16] = f2bf(acc_o[n][r] * inv);
  }
}

// ---------------------------------------------------------------------------
// LayerNorm, wave-per-token (no LDS, no barriers). 4 tokens per 256-thr block.
// ---------------------------------------------------------------------------
__global__ __launch_bounds__(256) void ln_kernel(
    const float* __restrict__ x, const unsigned short* __restrict__ o,
    float* __restrict__ out, unsigned short* __restrict__ outb,
    const float* __restrict__ g, const float* __restrict__ bta) {
  int lane = threadIdx.x & 63, wave = threadIdx.x >> 6;
  int n = blockIdx.x * 4 + wave;
  size_t base = (size_t)n * DMODEL;

  float v[12];
  float sum = 0.f;
  #pragma unroll
  for (int c = 0; c < 3; ++c) {
    int off = c * 256 + lane * 4;
    float4 xv = *(const float4*)(x + base + off);
    v[c * 4 + 0] = xv.x; v[c * 4 + 1] = xv.y;
    v[c * 4 + 2] = xv.z; v[c * 4 + 3] = xv.w;
    if (o) {
      ushortx4 ov = *(const ushortx4*)(o + base + off);
      #pragma unroll
      for (int j = 0; j < 4; ++j) v[c * 4 + j] += bf2f(ov[j]);
    }
    #pragma unroll
    for (int j = 0; j < 4; ++j) sum += v[c * 4 + j];
  }
  #pragma unroll
  for (int s = 1; s < 64; s <<= 1) sum += __shfl_xor(sum, s);
  float mu = sum * (1.0f / DMODEL);
  float var = 0.f;
  #pragma unroll
  for (int i = 0; i < 12; ++i) {
    float d = v[i] - mu;
    var += d * d;
  }
  #pragma unroll
  for (int s = 1; s < 64; s <<= 1) var += __shfl_xor(var, s);
  float rstd = rsqrtf(var * (1.0f / DMODEL) + 1e-5f);

  #pragma unroll
  for (int c = 0; c < 3; ++c) {
    int off = c * 256 + lane * 4;
    float4 gv = *(const float4*)(g + off);
    float4 bv = *(const float4*)(bta + off);
    float4 r;
    r.x = (v[c * 4 + 0] - mu) * rstd * gv.x + bv.x;
    r.y = (v[c * 4 + 1] - mu) * rstd * gv.y + bv.y;
    r.z = (v[c * 4 + 2] - mu) * rstd * gv.z + bv.z;
    r.w = (v[c * 4 + 3] - mu) * rstd * gv.w + bv.w;
    *(float4*)(out + base + off) = r;
    if (outb) {
      ushortx4 rb;
      rb[0] = f2bf(r.x); rb[1] = f2bf(r.y); rb[2] = f2bf(r.z); rb[3] = f2bf(r.w);
      *(ushortx4*)(outb + base + off) = rb;
    }
  }
}

// ---------------------------------------------------------------------------
// Mean-pool, stage 1: 8 sequence chunks of 64 rows -> partial[chunk][b][d]
// ---------------------------------------------------------------------------
__global__ __launch_bounds__(256) void pool_part_kernel(
    const float* __restrict__ xin, float* __restrict__ partial) {
  int blk = blockIdx.x;
  int chunk = blk / (BATCH * 3);
  int rem = blk % (BATCH * 3);
  int b = rem / 3, dc = rem % 3;
  int d = dc * 256 + threadIdx.x;
  float s_ = 0.f;
  for (int s = chunk * 64; s < chunk * 64 + 64; ++s)
    s_ += xin[(size_t)(b * SEQ + s) * DMODEL + d];
  partial[((size_t)chunk * BATCH + b) * DMODEL + d] = s_;
}

// ---------------------------------------------------------------------------
// Classifier: reduce 8 pool partials, logits = pooled @ Wfc + bfc, log_softmax
// ---------------------------------------------------------------------------
__global__ __launch_bounds__(256) void classifier_kernel(
    const float* __restrict__ partial, const float* __restrict__ Wfc,
    const float* __restrict__ bfc, float* __restrict__ out) {
  int b = blockIdx.x;
  int t = threadIdx.x;
  __shared__ float s0[256], s1[256];
  float acc0 = 0.f, acc1 = 0.f;
  for (int d = t; d < DMODEL; d += 256) {
    float p = 0.f;
    #pragma unroll
    for (int c = 0; c < 8; ++c)
      p += partial[((size_t)c * BATCH + b) * DMODEL + d];
    p *= (1.0f / SEQ);
    acc0 += p * Wfc[d * NCLS + 0];
    acc1 += p * Wfc[d * NCLS + 1];
  }
  s0[t] = acc0; s1[t] = acc1; __syncthreads();
  for (int off = 128; off; off >>= 1) {
    if (t < off) { s0[t] += s0[t + off]; s1[t] += s1[t + off]; }
    __syncthreads();
  }
  if (t == 0) {
    float l0 = s0[0] + bfc[0], l1 = s1[0] + bfc[1];
    float m = fmaxf(l0, l1);
    float lse = m + logf(expf(l0 - m) + expf(l1 - m));
    out[b * NCLS + 0] = l0 - lse;
    out[b * NCLS + 1] = l1 - lse;
  }
}

// ---------------------------------------------------------------------------
extern "C" void kernel_launch(void* const* d_in, const int* in_sizes, int n_in,
                              void* d_out, int out_size, void* d_ws, size_t ws_size,
                              hipStream_t stream) {
  const int*   text  = (const int*)d_in[0];
  const int*   mask  = (const int*)d_in[1];
  const float* emb   = (const float*)d_in[2];
  const float* Wq    = (const float*)d_in[3];
  const float* bq    = (const float*)d_in[4];
  const float* Wk    = (const float*)d_in[5];
  const float* bk    = (const float*)d_in[6];
  const float* Wv    = (const float*)d_in[7];
  const float* bv    = (const float*)d_in[8];
  const float* Wo    = (const float*)d_in[9];
  const float* bo    = (const float*)d_in[10];
  const float* W1    = (const float*)d_in[11];
  const float* b1    = (const float*)d_in[12];
  const float* W2    = (const float*)d_in[13];
  const float* b2    = (const float*)d_in[14];
  const float* ln1_g = (const float*)d_in[15];
  const float* ln1_b = (const float*)d_in[16];
  const float* ln2_g = (const float*)d_in[17];
  const float* ln2_b = (const float*)d_in[18];
  const float* lnf_g = (const float*)d_in[19];
  const float* lnf_b = (const float*)d_in[20];
  const float* Wfc   = (const float*)d_in[21];
  const float* bfc   = (const float*)d_in[22];

  const size_t ND = (size_t)NTOK * DMODEL;
  const size_t NF = (size_t)NTOK * FFDIM;
  const size_t WDD = (size_t)DMODEL * DMODEL;
  const size_t WDF = (size_t)DMODEL * FFDIM;

  float* xf      = (float*)d_ws;                  // [N,D] f32 residual
  float* partial = xf + ND;                       // [8][B][D] pool partials
  unsigned short* xb   = (unsigned short*)(partial + 8 * BATCH * DMODEL);
  unsigned short* qkvb = xb + ND;                 // [N,2304]; also o/ffn2 out
  unsigned short* vTb  = qkvb + (size_t)NTOK * QKVN;  // [B*H*64][SEQ]
  unsigned short* aob  = vTb + ND;                // [N,D] attention out
  unsigned short* h1b  = aob + ND;                // [N,FF]
  unsigned short* wqkvT = h1b + NF;               // 4 x [2304][768]
  unsigned short* woT  = wqkvT + 4 * 3 * WDD;     // 4 x [768][768]
  unsigned short* w1T  = woT + 4 * WDD;           // 4 x [FF][D]
  unsigned short* w2T  = w1T + 4 * WDF;           // 4 x [D][FF]
  unsigned short* ob   = qkvb;                    // alias: o-proj/ffn2 output

  dim3 gD64(DMODEL / 64, NTOK / BM);   // (12, 32) = 384 blocks, TBN=64
  dim3 gQKV(QKVN / 128, NTOK / BM);    // (18, 32) = 576 blocks, TBN=128
  dim3 gF(FFDIM / 128, NTOK / BM);     // (24, 32) = 768 blocks, TBN=128

  embed_kernel<<<NTOK, 256, 0, stream>>>(text, emb, xf, xb);
  wconv_all_kernel<<<4 * 1728, 256, 0, stream>>>(
      Wq, Wk, Wv, Wo, W1, W2, wqkvT, woT, w1T, w2T);

  for (int l = 0; l < LAYERS; ++l) {
    // fused QKV projection (V written transposed to vTb)
    gemm_mfma_kernel<128><<<gQKV, 256, 0, stream>>>(
        xb, wqkvT + (size_t)l * 3 * WDD, bq + l * DMODEL, bk + l * DMODEL,
        bv + l * DMODEL, qkvb, vTb, NTOK, QKVN, DMODEL, 1, 0);

    attention_mfma_kernel<<<BATCH * NHEAD * (SEQ / 64), 256, 0, stream>>>(
        qkvb, vTb, mask, aob);

    gemm_mfma_kernel<64><<<gD64, 256, 0, stream>>>(
        aob, woT + (size_t)l * WDD, bo + l * DMODEL, nullptr, nullptr,
        ob, nullptr, NTOK, DMODEL, DMODEL, 1, 0);
    ln_kernel<<<NTOK / 4, 256, 0, stream>>>(xf, ob, xf, xb,
                                            ln1_g + l * DMODEL, ln1_b + l * DMODEL);
    gemm_mfma_kernel<128><<<gF, 256, 0, stream>>>(
        xb, w1T + (size_t)l * WDF, b1 + l * FFDIM, nullptr, nullptr,
        h1b, nullptr, NTOK, FFDIM, DMODEL, 1, 1);
    gemm_mfma_kernel<64><<<gD64, 256, 0, stream>>>(
        h1b, w2T + (size_t)l * WDF, b2 + l * DMODEL, nullptr, nullptr,
        ob, nullptr, NTOK, DMODEL, FFDIM, 1, 0);
    ln_kernel<<<NTOK / 4, 256, 0, stream>>>(xf, ob, xf, xb,
                                            ln2_g + l * DMODEL, ln2_b + l * DMODEL);
  }

  // final LN in-place on xf, then pool partials + classify
  ln_kernel<<<NTOK / 4, 256, 0, stream>>>(xf, nullptr, xf, nullptr, lnf_g, lnf_b);
  pool_part_kernel<<<8 * BATCH * 3, 256, 0, stream>>>(xf, partial);
  classifier_kernel<<<BATCH, 256, 0, stream>>>(partial, Wfc, bfc, (float*)d_out);
}